// Round 1
// baseline (3845.663 us; speedup 1.0000x reference)
//
#include <hip/hip_runtime.h>
#include <hip/hip_bf16.h>

#define BB 4
#define CINsz 512
#define HH 63
#define NN 3969          // 63*63
#define CI 256
#define CO 512
#define NK 81
#define SCALE 0.0625f    // 256^-0.5
#define BN_EPS 1e-5f

// ---------------- K1: fused conv1x1 for qk (with BN) and value ----------------
// grid (ceil(N/256)=16, 512/8=64, B), block 256. Each thread: 1 spatial pos, 8 out chans.
__global__ __launch_bounds__(256) void k_qkv(
    const float* __restrict__ x, const float* __restrict__ Wk, const float* __restrict__ bk,
    const float* __restrict__ gamma, const float* __restrict__ beta,
    const float* __restrict__ Wv, const float* __restrict__ bv,
    float* __restrict__ qk, float* __restrict__ value)
{
    int n  = blockIdx.x * 256 + threadIdx.x;
    int o0 = blockIdx.y * 8;          // 0..511 step 8 over [qk(256) | value(256)]
    int b  = blockIdx.z;
    if (n >= NN) return;
    bool isK = (o0 < CI);
    const float* W = isK ? Wk : Wv;
    int oo = isK ? o0 : (o0 - CI);
    const float* Wr = W + (size_t)oo * CINsz;
    const float* xb = x + (size_t)b * CINsz * NN + n;

    float acc[8];
#pragma unroll
    for (int g = 0; g < 8; ++g) acc[g] = 0.f;

    for (int c = 0; c < CINsz; ++c) {
        float xv = xb[(size_t)c * NN];
#pragma unroll
        for (int g = 0; g < 8; ++g) acc[g] += Wr[g * CINsz + c] * xv;
    }

    if (isK) {
#pragma unroll
        for (int g = 0; g < 8; ++g) {
            int o = oo + g;
            float s = gamma[o] / sqrtf(1.0f + BN_EPS);
            qk[(size_t)b * CI * NN + (size_t)o * NN + n] = (acc[g] + bk[o]) * s + beta[o];
        }
    } else {
#pragma unroll
        for (int g = 0; g < 8; ++g) {
            int o = oo + g;
            value[(size_t)b * CI * NN + (size_t)o * NN + n] = acc[g] + bv[o];
        }
    }
}

// ---------------- K2: exact 7x7 average pool to 9x9 ----------------
__global__ void k_pool(const float* __restrict__ value, float* __restrict__ pooled)
{
    int idx = blockIdx.x * 256 + threadIdx.x;
    if (idx >= BB * CI * NK) return;
    int k = idx % NK; int c = (idx / NK) % CI; int b = idx / (NK * CI);
    int ky = k / 9, kx = k % 9;
    const float* base = value + (size_t)b * CI * NN + (size_t)c * NN + (ky * 7) * HH + kx * 7;
    float s = 0.f;
    for (int i = 0; i < 7; ++i)
#pragma unroll
        for (int j = 0; j < 7; ++j) s += base[i * HH + j];
    pooled[idx] = s * (1.0f / 49.0f);
}

// ---------------- K3: v2 = Wv2 @ pooled + bv2 ----------------
__global__ void k_v2(const float* __restrict__ Wv2, const float* __restrict__ bv2,
                     const float* __restrict__ pooled, float* __restrict__ v2)
{
    int idx = blockIdx.x * 256 + threadIdx.x;
    if (idx >= BB * CI * NK) return;
    int k = idx % NK; int o = (idx / NK) % CI; int b = idx / (NK * CI);
    const float* pb = pooled + (size_t)b * CI * NK + k;
    const float* wr = Wv2 + (size_t)o * CI;
    float acc = bv2[o];
    for (int c = 0; c < CI; ++c) acc += wr[c] * pb[c * NK];
    v2[idx] = acc;   // layout [B][CI][81]
}

// ---------------- K4: Z[b][k][o] = sum_c Ww[o][c] * v2[b][c][k] ----------------
__global__ void k_Z(const float* __restrict__ Ww, const float* __restrict__ v2,
                    float* __restrict__ Z)
{
    int idx = blockIdx.x * 256 + threadIdx.x;
    if (idx >= BB * NK * CO) return;
    int o = idx % CO; int k = (idx / CO) % NK; int b = idx / (CO * NK);
    const float* v2b = v2 + (size_t)b * CI * NK + k;
    const float* wr = Ww + (size_t)o * CI;
    float acc = 0.f;
    for (int c = 0; c < CI; ++c) acc += wr[c] * v2b[c * NK];
    Z[idx] = acc;   // layout [B][81][CO]
}

// ---------------- K5: simv = softmax_k( scale * value^T v2 )  [B][N][81] ----------------
// one block (128 thr) per (n,b); threads 0..80 compute dots; LDS tree softmax.
__global__ __launch_bounds__(128) void k_simv(const float* __restrict__ value,
                                              const float* __restrict__ v2,
                                              float* __restrict__ simv)
{
    int n = blockIdx.x, b = blockIdx.y;
    int k = threadIdx.x;
    __shared__ float red[128];
    float acc = -1e30f;
    if (k < NK) {
        const float* vcol = value + (size_t)b * CI * NN + n;
        const float* v2b  = v2 + (size_t)b * CI * NK + k;
        float a = 0.f;
        for (int c = 0; c < CI; ++c) a += vcol[(size_t)c * NN] * v2b[c * NK];
        acc = a * SCALE;
    }
    red[k] = acc; __syncthreads();
    for (int s2 = 64; s2 > 0; s2 >>= 1) { if (k < s2) red[k] = fmaxf(red[k], red[k + s2]); __syncthreads(); }
    float mx = red[0]; __syncthreads();
    float p = (k < NK) ? expf(acc - mx) : 0.f;
    red[k] = p; __syncthreads();
    for (int s2 = 64; s2 > 0; s2 >>= 1) { if (k < s2) red[k] += red[k + s2]; __syncthreads(); }
    float inv = 1.0f / red[0];
    if (k < NK) simv[(size_t)b * NN * NK + (size_t)n * NK + k] = p * inv;
}

// ---------------- K6: flash attention: simnew = softmax_m(scale*qk^T qk) @ simv ----------------
// QTILE=MTILE=32, block 256. thread(tr=tid>>4, tc=tid&15): 2x2 S tile, acc[2 rows][6 k-cols] in regs.
__global__ __launch_bounds__(256) void k_flash(const float* __restrict__ qk,
                                               const float* __restrict__ simv,
                                               float* __restrict__ simnew)
{
    const int b = blockIdx.y;
    const int qbase = blockIdx.x * 32;
    const int tid = threadIdx.x;
    const int tr = tid >> 4;     // rows n_loc = 2*tr + r
    const int tc = tid & 15;     // cols m_loc = 2*tc + j

    __shared__ float q_lds[64][32];    // [c_chunk][n], pre-scaled by SCALE
    __shared__ float k_lds[64][32];    // [c_chunk][m]
    __shared__ float p_lds[32][33];    // [m][n] (transposed, padded)
    __shared__ float sv_lds[32][NK];   // simv tile
    __shared__ float m_lds[32];
    __shared__ float l_lds[32];

    float acc[2][6];
#pragma unroll
    for (int r = 0; r < 2; ++r)
#pragma unroll
        for (int t = 0; t < 6; ++t) acc[r][t] = 0.f;
    if (tid < 32) { m_lds[tid] = -1e30f; l_lds[tid] = 0.f; }

    const float* qkb = qk + (size_t)b * CI * NN;
    const float* svb = simv + (size_t)b * NN * NK;

    for (int mbase = 0; mbase < NN; mbase += 32) {
        __syncthreads();  // protect sv_lds/p_lds reuse + m/l init
        // stage simv tile
        for (int idx = tid; idx < 32 * NK; idx += 256) {
            int mm = idx / NK, kk = idx % NK;
            int m = mbase + mm;
            sv_lds[mm][kk] = (m < NN) ? svb[(size_t)m * NK + kk] : 0.f;
        }
        float s00 = 0.f, s01 = 0.f, s10 = 0.f, s11 = 0.f;
        for (int cb = 0; cb < CI; cb += 64) {
            __syncthreads();  // previous chunk fully consumed
            for (int idx = tid; idx < 64 * 32; idx += 256) {
                int cc = idx >> 5, u = idx & 31;
                int n = qbase + u;
                q_lds[cc][u] = (n < NN) ? qkb[(size_t)(cb + cc) * NN + n] * SCALE : 0.f;
                int m = mbase + u;
                k_lds[cc][u] = (m < NN) ? qkb[(size_t)(cb + cc) * NN + m] : 0.f;
            }
            __syncthreads();
#pragma unroll
            for (int cc = 0; cc < 64; ++cc) {
                float2 qv = *(const float2*)&q_lds[cc][tr * 2];
                float2 kv = *(const float2*)&k_lds[cc][tc * 2];
                s00 += qv.x * kv.x; s01 += qv.x * kv.y;
                s10 += qv.y * kv.x; s11 += qv.y * kv.y;
            }
        }
        // mask invalid keys
        if (mbase + tc * 2     >= NN) { s00 = -1e30f; s10 = -1e30f; }
        if (mbase + tc * 2 + 1 >= NN) { s01 = -1e30f; s11 = -1e30f; }
        // row max across the 16 tc lanes (in-wave: tc = low 4 lane bits)
        float rmax0 = fmaxf(s00, s01), rmax1 = fmaxf(s10, s11);
#pragma unroll
        for (int off = 1; off < 16; off <<= 1) {
            rmax0 = fmaxf(rmax0, __shfl_xor(rmax0, off));
            rmax1 = fmaxf(rmax1, __shfl_xor(rmax1, off));
        }
        int n0 = tr * 2, n1 = tr * 2 + 1;
        float mo0 = m_lds[n0], mo1 = m_lds[n1];
        float mn0 = fmaxf(mo0, rmax0), mn1 = fmaxf(mo1, rmax1);
        float al0 = expf(mo0 - mn0), al1 = expf(mo1 - mn1);
        float p00 = expf(s00 - mn0), p01 = expf(s01 - mn0);
        float p10 = expf(s10 - mn1), p11 = expf(s11 - mn1);
        float ps0 = p00 + p01, ps1 = p10 + p11;
#pragma unroll
        for (int off = 1; off < 16; off <<= 1) {
            ps0 += __shfl_xor(ps0, off);
            ps1 += __shfl_xor(ps1, off);
        }
        if (tc == 0) {
            m_lds[n0] = mn0; m_lds[n1] = mn1;
            l_lds[n0] = l_lds[n0] * al0 + ps0;
            l_lds[n1] = l_lds[n1] * al1 + ps1;
        }
        p_lds[tc * 2    ][n0] = p00; p_lds[tc * 2    ][n1] = p10;
        p_lds[tc * 2 + 1][n0] = p01; p_lds[tc * 2 + 1][n1] = p11;
        __syncthreads();  // p/m/l visible everywhere (safety)
        // rescale + PV
#pragma unroll
        for (int t = 0; t < 6; ++t) { acc[0][t] *= al0; acc[1][t] *= al1; }
        for (int m = 0; m < 32; ++m) {
            float pr0 = p_lds[m][n0];
            float pr1 = p_lds[m][n1];
#pragma unroll
            for (int t = 0; t < 5; ++t) {
                float sv = sv_lds[m][tc + 16 * t];
                acc[0][t] += pr0 * sv;
                acc[1][t] += pr1 * sv;
            }
            if (tc == 0) {
                float sv = sv_lds[m][80];
                acc[0][5] += pr0 * sv;
                acc[1][5] += pr1 * sv;
            }
        }
    }
    // epilogue: divide by l, store
    float li0 = 1.0f / l_lds[tr * 2];
    float li1 = 1.0f / l_lds[tr * 2 + 1];
    int gn0 = qbase + tr * 2, gn1 = gn0 + 1;
    if (gn0 < NN) {
        float* o0 = simnew + (size_t)b * NN * NK + (size_t)gn0 * NK;
#pragma unroll
        for (int t = 0; t < 5; ++t) o0[tc + 16 * t] = acc[0][t] * li0;
        if (tc == 0) o0[80] = acc[0][5] * li0;
    }
    if (gn1 < NN) {
        float* o1 = simnew + (size_t)b * NN * NK + (size_t)gn1 * NK;
#pragma unroll
        for (int t = 0; t < 5; ++t) o1[tc + 16 * t] = acc[1][t] * li1;
        if (tc == 0) o1[80] = acc[1][5] * li1;
    }
}

// ---------------- K7: out[b][o][n] = bw[o] + sum_k simnew[b][n][k] * Z[b][k][o] ----------------
// grid (63, 4, B), block 256: n-tile 64 x o-tile 128; simnew tile staged in LDS.
__global__ __launch_bounds__(256) void k_out(const float* __restrict__ simnew,
                                             const float* __restrict__ Z,
                                             const float* __restrict__ bw,
                                             float* __restrict__ out)
{
    int b = blockIdx.z;
    int nbase = blockIdx.x * 64;
    int obase = blockIdx.y * 128;
    int tid = threadIdx.x;
    int nn = tid & 63;
    int og = tid >> 6;   // 0..3
    __shared__ float sn[64][NK];
    for (int idx = tid; idx < 64 * NK; idx += 256) {
        int u = idx / NK, kk = idx % NK;
        int n = nbase + u;
        sn[u][kk] = (n < NN) ? simnew[(size_t)b * NN * NK + (size_t)n * NK + kk] : 0.f;
    }
    __syncthreads();
    int n = nbase + nn;
    const float* Zb = Z + (size_t)b * NK * CO;
    for (int j = 0; j < 32; ++j) {
        int o = obase + og * 32 + j;
        float a = bw[o];
        for (int kk = 0; kk < NK; ++kk)
            a += sn[nn][kk] * Zb[(size_t)kk * CO + o];
        if (n < NN) out[(size_t)b * CO * NN + (size_t)o * NN + n] = a;
    }
}

extern "C" void kernel_launch(void* const* d_in, const int* in_sizes, int n_in,
                              void* d_out, int out_size, void* d_ws, size_t ws_size,
                              hipStream_t stream)
{
    const float* x     = (const float*)d_in[0];
    const float* Wk    = (const float*)d_in[1];
    const float* bk    = (const float*)d_in[2];
    const float* gamma = (const float*)d_in[3];
    const float* beta  = (const float*)d_in[4];
    const float* Wv    = (const float*)d_in[5];
    const float* bv    = (const float*)d_in[6];
    const float* Wv2   = (const float*)d_in[7];
    const float* bv2   = (const float*)d_in[8];
    const float* Ww    = (const float*)d_in[9];
    const float* bw    = (const float*)d_in[10];
    float* out = (float*)d_out;

    float* ws     = (float*)d_ws;
    float* qk     = ws;                                   // B*CI*N
    float* value  = qk     + (size_t)BB * CI * NN;        // B*CI*N
    float* pooled = value  + (size_t)BB * CI * NN;        // B*CI*81
    float* v2     = pooled + (size_t)BB * CI * NK;        // B*CI*81
    float* Z      = v2     + (size_t)BB * CI * NK;        // B*81*CO
    float* simv   = Z      + (size_t)BB * NK * CO;        // B*N*81
    float* simnew = simv   + (size_t)BB * NN * NK;        // B*N*81

    k_qkv<<<dim3(16, 64, BB), 256, 0, stream>>>(x, Wk, bk, gamma, beta, Wv, bv, qk, value);
    k_pool<<<dim3((BB * CI * NK + 255) / 256), 256, 0, stream>>>(value, pooled);
    k_v2<<<dim3((BB * CI * NK + 255) / 256), 256, 0, stream>>>(Wv2, bv2, pooled, v2);
    k_Z<<<dim3((BB * NK * CO + 255) / 256), 256, 0, stream>>>(Ww, v2, Z);
    k_simv<<<dim3(NN, BB), 128, 0, stream>>>(value, v2, simv);
    k_flash<<<dim3((NN + 31) / 32, BB), 256, 0, stream>>>(qk, simv, simnew);
    k_out<<<dim3(63, 4, BB), 256, 0, stream>>>(simnew, Z, bw, out);
}

// Round 2
// 948.733 us; speedup vs baseline: 4.0535x; 4.0535x over previous
//
#include <hip/hip_runtime.h>
#include <hip/hip_bf16.h>

#define BB 4
#define CINsz 512
#define HH 63
#define NN 3969          // 63*63
#define NPAD 4032        // 63 * 64 (kv/q tile padding)
#define CI 256
#define CO 512
#define NK 81
#define SCALE 0.0625f    // 256^-0.5
#define BN_EPS 1e-5f

typedef __bf16 bf16x8 __attribute__((ext_vector_type(8)));
typedef float f32x4 __attribute__((ext_vector_type(4)));
typedef unsigned short ushort8 __attribute__((ext_vector_type(8)));

__device__ inline unsigned short f2bf(float x) {
    union { float f; unsigned int u; } v; v.f = x;
    unsigned int r = v.u + 0x7FFF + ((v.u >> 16) & 1);
    return (unsigned short)(r >> 16);
}

// ---------------- K1: fused conv1x1 for qk (bf16 [B][NPAD][CI], BN folded) and value (fp32) ----
__global__ __launch_bounds__(256) void k_qkv(
    const float* __restrict__ x, const float* __restrict__ Wk, const float* __restrict__ bk,
    const float* __restrict__ gamma, const float* __restrict__ beta,
    const float* __restrict__ Wv, const float* __restrict__ bv,
    unsigned short* __restrict__ qkbf, float* __restrict__ value)
{
    int n  = blockIdx.x * 256 + threadIdx.x;
    int o0 = blockIdx.y * 8;          // 0..511 step 8 over [qk(256) | value(256)]
    int b  = blockIdx.z;
    if (n >= NN) return;
    bool isK = (o0 < CI);
    const float* W = isK ? Wk : Wv;
    int oo = isK ? o0 : (o0 - CI);
    const float* Wr = W + (size_t)oo * CINsz;
    const float* xb = x + (size_t)b * CINsz * NN + n;

    float acc[8];
#pragma unroll
    for (int g = 0; g < 8; ++g) acc[g] = 0.f;

    for (int c = 0; c < CINsz; ++c) {
        float xv = xb[(size_t)c * NN];
#pragma unroll
        for (int g = 0; g < 8; ++g) acc[g] += Wr[g * CINsz + c] * xv;
    }

    if (isK) {
        ushort8 w8;
#pragma unroll
        for (int g = 0; g < 8; ++g) {
            int o = oo + g;
            float s = gamma[o] / sqrtf(1.0f + BN_EPS);
            w8[g] = f2bf((acc[g] + bk[o]) * s + beta[o]);
        }
        *reinterpret_cast<ushort8*>(&qkbf[((size_t)b * NPAD + n) * CI + oo]) = w8;
    } else {
#pragma unroll
        for (int g = 0; g < 8; ++g) {
            int o = oo + g;
            value[(size_t)b * CI * NN + (size_t)o * NN + n] = acc[g] + bv[o];
        }
    }
}

// ---------------- K2: exact 7x7 average pool to 9x9 ----------------
__global__ void k_pool(const float* __restrict__ value, float* __restrict__ pooled)
{
    int idx = blockIdx.x * 256 + threadIdx.x;
    if (idx >= BB * CI * NK) return;
    int k = idx % NK; int c = (idx / NK) % CI; int b = idx / (NK * CI);
    int ky = k / 9, kx = k % 9;
    const float* base = value + (size_t)b * CI * NN + (size_t)c * NN + (ky * 7) * HH + kx * 7;
    float s = 0.f;
    for (int i = 0; i < 7; ++i)
#pragma unroll
        for (int j = 0; j < 7; ++j) s += base[i * HH + j];
    pooled[idx] = s * (1.0f / 49.0f);
}

// ---------------- K3: v2 = Wv2 @ pooled + bv2 ----------------
__global__ void k_v2(const float* __restrict__ Wv2, const float* __restrict__ bv2,
                     const float* __restrict__ pooled, float* __restrict__ v2)
{
    int idx = blockIdx.x * 256 + threadIdx.x;
    if (idx >= BB * CI * NK) return;
    int k = idx % NK; int o = (idx / NK) % CI; int b = idx / (NK * CI);
    const float* pb = pooled + (size_t)b * CI * NK + k;
    const float* wr = Wv2 + (size_t)o * CI;
    float acc = bv2[o];
    for (int c = 0; c < CI; ++c) acc += wr[c] * pb[c * NK];
    v2[idx] = acc;   // layout [B][CI][81]
}

// ---------------- K4: Z[b][k][o] = sum_c Ww[o][c] * v2[b][c][k] ----------------
__global__ void k_Z(const float* __restrict__ Ww, const float* __restrict__ v2,
                    float* __restrict__ Z)
{
    int idx = blockIdx.x * 256 + threadIdx.x;
    if (idx >= BB * NK * CO) return;
    int o = idx % CO; int k = (idx / CO) % NK; int b = idx / (CO * NK);
    const float* v2b = v2 + (size_t)b * CI * NK + k;
    const float* wr = Ww + (size_t)o * CI;
    float acc = 0.f;
    for (int c = 0; c < CI; ++c) acc += wr[c] * v2b[c * NK];
    Z[idx] = acc;   // layout [B][81][CO]
}

// ---------------- K5: simv = softmax_k( scale * value^T v2 )  [B][N][81] fp32 ----------------
__global__ __launch_bounds__(128) void k_simv(const float* __restrict__ value,
                                              const float* __restrict__ v2,
                                              float* __restrict__ simv)
{
    int n = blockIdx.x, b = blockIdx.y;
    int k = threadIdx.x;
    __shared__ float red[128];
    float acc = -1e30f;
    if (k < NK) {
        const float* vcol = value + (size_t)b * CI * NN + n;
        const float* v2b  = v2 + (size_t)b * CI * NK + k;
        float a = 0.f;
        for (int c = 0; c < CI; ++c) a += vcol[(size_t)c * NN] * v2b[c * NK];
        acc = a * SCALE;
    }
    red[k] = acc; __syncthreads();
    for (int s2 = 64; s2 > 0; s2 >>= 1) { if (k < s2) red[k] = fmaxf(red[k], red[k + s2]); __syncthreads(); }
    float mx = red[0]; __syncthreads();
    float p = (k < NK) ? expf(acc - mx) : 0.f;
    red[k] = p; __syncthreads();
    for (int s2 = 64; s2 > 0; s2 >>= 1) { if (k < s2) red[k] += red[k + s2]; __syncthreads(); }
    float inv = 1.0f / red[0];
    if (k < NK) simv[(size_t)b * NN * NK + (size_t)n * NK + k] = p * inv;
}

// ---------------- K6: MFMA flash attention: simnew = softmax_m(scale*qk^T qk) @ simv --------
// Block: 256 thr = 4 waves, 64 q-rows (16/wave), KV tile 64 keys.
// k_lds  [64 key][256 c]  bf16, XOR-swizzled rows (hw ^= (row&7)<<3)
// sv_lds [96 col][64 key] bf16, swizzled  (pad cols 81..95 zeroed once)
// p_lds  per-wave [16 row][64 key] bf16, swizzled
__global__ __launch_bounds__(256) void k_flash(const unsigned short* __restrict__ qkbf,
                                               const float* __restrict__ simv,
                                               float* __restrict__ simnew)
{
    const int b = blockIdx.y;
    const int qbase = blockIdx.x * 64;
    const int tid = threadIdx.x;
    const int w = tid >> 6, lane = tid & 63, lg = lane >> 4, lr = lane & 15;

    __shared__ unsigned short k_lds[64 * 256];
    __shared__ unsigned short sv_lds[96 * 64];
    __shared__ unsigned short p_lds[4 * 16 * 64];

    const unsigned short* qkb = qkbf + (size_t)b * NPAD * CI;
    const float* svb = simv + (size_t)b * NN * NK;

    // Q fragments in registers: A[i=lr][k=8*lg+j], 8 c-steps of 32
    bf16x8 qa[8];
    {
        const unsigned short* qp = qkb + (size_t)(qbase + w * 16 + lr) * CI + lg * 8;
#pragma unroll
        for (int s = 0; s < 8; ++s) qa[s] = *reinterpret_cast<const bf16x8*>(qp + s * 32);
    }

    f32x4 acc[6];
#pragma unroll
    for (int jt = 0; jt < 6; ++jt) acc[jt] = (f32x4){0.f, 0.f, 0.f, 0.f};
    float m_run[4], l_run[4];
#pragma unroll
    for (int r = 0; r < 4; ++r) { m_run[r] = -1e30f; l_run[r] = 0.f; }

    // zero sv pad cols 81..95 (never written in the loop)
    for (int idx = tid; idx < 15 * 64; idx += 256) {
        int k = 81 + (idx >> 6), m = idx & 63;
        sv_lds[k * 64 + (m ^ ((k & 7) << 3))] = 0;
    }

    for (int mbase = 0; mbase < NN; mbase += 64) {
        __syncthreads();   // previous iter's compute done; LDS reusable
        // ---- stage K tile (64x256 bf16 = 32KB), swizzled write, linear read from global
#pragma unroll
        for (int it = 0; it < 8; ++it) {
            int q = it * 256 + tid;                 // 16B chunk id
            int row = q >> 5, hwc = (q & 31) << 3;  // halfword col
            ushort8 v = *reinterpret_cast<const ushort8*>(qkb + (size_t)(mbase + row) * CI + hwc);
            *reinterpret_cast<ushort8*>(&k_lds[row * 256 + (hwc ^ ((row & 7) << 3))]) = v;
        }
        // ---- stage SV tile transposed: sv_lds[col k][key m]
        for (int idx = tid; idx < 64 * NK; idx += 256) {
            int m = idx / NK, k = idx - m * NK;
            int mg = mbase + m; if (mg > NN - 1) mg = NN - 1;
            sv_lds[k * 64 + (m ^ ((k & 7) << 3))] = f2bf(svb[(size_t)mg * NK + k]);
        }
        __syncthreads();

        // ---- QK^T: 4 key-tiles x 8 c-steps
        f32x4 s_acc[4];
#pragma unroll
        for (int t = 0; t < 4; ++t) s_acc[t] = (f32x4){0.f, 0.f, 0.f, 0.f};
#pragma unroll
        for (int s = 0; s < 8; ++s) {
#pragma unroll
            for (int t = 0; t < 4; ++t) {
                int row = t * 16 + lr;
                int hw = s * 32 + lg * 8;
                bf16x8 kf = *reinterpret_cast<const bf16x8*>(
                    &k_lds[row * 256 + (hw ^ ((row & 7) << 3))]);
                s_acc[t] = __builtin_amdgcn_mfma_f32_16x16x32_bf16(qa[s], kf, s_acc[t], 0, 0, 0);
            }
        }
        // scale + mask invalid keys (only last tile)
#pragma unroll
        for (int t = 0; t < 4; ++t) {
#pragma unroll
            for (int r = 0; r < 4; ++r) s_acc[t][r] *= SCALE;
        }
        if (mbase + 64 > NN) {
#pragma unroll
            for (int t = 0; t < 4; ++t)
                if (mbase + t * 16 + lr >= NN) {
#pragma unroll
                    for (int r = 0; r < 4; ++r) s_acc[t][r] = -1e30f;
                }
        }
        // ---- online softmax (rows 4*lg+r; cols spread over 16-lane group)
        float al[4], psum[4];
#pragma unroll
        for (int r = 0; r < 4; ++r) {
            float m0 = fmaxf(fmaxf(s_acc[0][r], s_acc[1][r]), fmaxf(s_acc[2][r], s_acc[3][r]));
#pragma unroll
            for (int off = 1; off < 16; off <<= 1) m0 = fmaxf(m0, __shfl_xor(m0, off));
            float mn = fmaxf(m_run[r], m0);
            al[r] = __expf(m_run[r] - mn);
            m_run[r] = mn;
            psum[r] = 0.f;
        }
        unsigned short* pw = p_lds + w * (16 * 64);
#pragma unroll
        for (int t = 0; t < 4; ++t) {
#pragma unroll
            for (int r = 0; r < 4; ++r) {
                float p = __expf(s_acc[t][r] - m_run[r]);
                psum[r] += p;
                int row = lg * 4 + r, col = t * 16 + lr;
                pw[row * 64 + (col ^ ((row & 7) << 3))] = f2bf(p);
            }
        }
#pragma unroll
        for (int r = 0; r < 4; ++r) {
            float ps = psum[r];
#pragma unroll
            for (int off = 1; off < 16; off <<= 1) ps += __shfl_xor(ps, off);
            l_run[r] = l_run[r] * al[r] + ps;
        }
        // ---- rescale running O, then PV (wave-private p_lds: no barrier needed)
#pragma unroll
        for (int jt = 0; jt < 6; ++jt) {
#pragma unroll
            for (int r = 0; r < 4; ++r) acc[jt][r] *= al[r];
        }
#pragma unroll
        for (int kb = 0; kb < 2; ++kb) {
            int hw = kb * 32 + lg * 8;
            bf16x8 pa = *reinterpret_cast<const bf16x8*>(
                &pw[lr * 64 + (hw ^ ((lr & 7) << 3))]);
#pragma unroll
            for (int jt = 0; jt < 6; ++jt) {
                int cr = jt * 16 + lr;
                bf16x8 svf = *reinterpret_cast<const bf16x8*>(
                    &sv_lds[cr * 64 + (hw ^ ((cr & 7) << 3))]);
                acc[jt] = __builtin_amdgcn_mfma_f32_16x16x32_bf16(pa, svf, acc[jt], 0, 0, 0);
            }
        }
    }
    // ---- epilogue: divide by l, store fp32 simnew [B][N][81]
#pragma unroll
    for (int r = 0; r < 4; ++r) {
        int row = qbase + w * 16 + lg * 4 + r;
        if (row < NN) {
            float inv = 1.0f / l_run[r];
            float* op = simnew + (size_t)b * NN * NK + (size_t)row * NK;
#pragma unroll
            for (int jt = 0; jt < 6; ++jt) {
                int col = jt * 16 + lr;
                if (col < NK) op[col] = acc[jt][r] * inv;
            }
        }
    }
}

// ---------------- K7: out[b][o][n] = bw[o] + sum_k simnew[b][n][k] * Z[b][k][o] ----------------
__global__ __launch_bounds__(256) void k_out(const float* __restrict__ simnew,
                                             const float* __restrict__ Z,
                                             const float* __restrict__ bw,
                                             float* __restrict__ out)
{
    int b = blockIdx.z;
    int nbase = blockIdx.x * 64;
    int obase = blockIdx.y * 128;
    int tid = threadIdx.x;
    int nn = tid & 63;
    int og = tid >> 6;   // 0..3
    __shared__ float sn[64][NK];
    for (int idx = tid; idx < 64 * NK; idx += 256) {
        int u = idx / NK, kk = idx % NK;
        int n = nbase + u;
        sn[u][kk] = (n < NN) ? simnew[(size_t)b * NN * NK + (size_t)n * NK + kk] : 0.f;
    }
    __syncthreads();
    int n = nbase + nn;
    const float* Zb = Z + (size_t)b * NK * CO;
    for (int j = 0; j < 32; ++j) {
        int o = obase + og * 32 + j;
        float a = bw[o];
        for (int kk = 0; kk < NK; ++kk)
            a += sn[nn][kk] * Zb[(size_t)kk * CO + o];
        if (n < NN) out[(size_t)b * CO * NN + (size_t)o * NN + n] = a;
    }
}

extern "C" void kernel_launch(void* const* d_in, const int* in_sizes, int n_in,
                              void* d_out, int out_size, void* d_ws, size_t ws_size,
                              hipStream_t stream)
{
    const float* x     = (const float*)d_in[0];
    const float* Wk    = (const float*)d_in[1];
    const float* bk    = (const float*)d_in[2];
    const float* gamma = (const float*)d_in[3];
    const float* beta  = (const float*)d_in[4];
    const float* Wv    = (const float*)d_in[5];
    const float* bv    = (const float*)d_in[6];
    const float* Wv2   = (const float*)d_in[7];
    const float* bv2   = (const float*)d_in[8];
    const float* Ww    = (const float*)d_in[9];
    const float* bw    = (const float*)d_in[10];
    float* out = (float*)d_out;

    unsigned short* qkbf = (unsigned short*)d_ws;               // B*NPAD*CI bf16
    float* value  = (float*)(qkbf + (size_t)BB * NPAD * CI);    // B*CI*N
    float* pooled = value  + (size_t)BB * CI * NN;              // B*CI*81
    float* v2     = pooled + (size_t)BB * CI * NK;              // B*CI*81
    float* Z      = v2     + (size_t)BB * CI * NK;              // B*81*CO
    float* simv   = Z      + (size_t)BB * NK * CO;              // B*N*81
    float* simnew = simv   + (size_t)BB * NN * NK;              // B*N*81

    k_qkv<<<dim3(16, 64, BB), 256, 0, stream>>>(x, Wk, bk, gamma, beta, Wv, bv, qkbf, value);
    k_pool<<<dim3((BB * CI * NK + 255) / 256), 256, 0, stream>>>(value, pooled);
    k_v2<<<dim3((BB * CI * NK + 255) / 256), 256, 0, stream>>>(Wv2, bv2, pooled, v2);
    k_Z<<<dim3((BB * NK * CO + 255) / 256), 256, 0, stream>>>(Ww, v2, Z);
    k_simv<<<dim3(NN, BB), 128, 0, stream>>>(value, v2, simv);
    k_flash<<<dim3(63, BB), 256, 0, stream>>>(qkbf, simv, simnew);
    k_out<<<dim3(63, 4, BB), 256, 0, stream>>>(simnew, Z, bw, out);
}

// Round 4
// 504.106 us; speedup vs baseline: 7.6287x; 1.8820x over previous
//
#include <hip/hip_runtime.h>
#include <hip/hip_bf16.h>

#define BB 4
#define CINsz 512
#define HH 63
#define NN 3969          // 63*63
#define NPAD 4032        // 63*64
#define CI 256
#define CO 512
#define NK 81
#define NKP 96           // padded k-dim
#define SCALE 0.0625f    // 256^-0.5
#define BN_EPS 1e-5f

typedef __bf16 bf16x8 __attribute__((ext_vector_type(8)));
typedef float f32x4 __attribute__((ext_vector_type(4)));
typedef unsigned short us8 __attribute__((ext_vector_type(8)));
typedef unsigned short us4 __attribute__((ext_vector_type(4)));

#define MFMA16(a, b, c) __builtin_amdgcn_mfma_f32_16x16x32_bf16((a), (b), (c), 0, 0, 0)

__device__ inline unsigned short f2bf(float x) {
    union { float f; unsigned int u; } v; v.f = x;
    unsigned int r = v.u + 0x7FFF + ((v.u >> 16) & 1);
    return (unsigned short)(r >> 16);
}
__device__ inline float bf2f(unsigned short u) {
    union { unsigned int u; float f; } v; v.u = ((unsigned int)u) << 16;
    return v.f;
}

// ---------------- k_prep: weights -> bf16, BN folded into Wk ----------------
__global__ __launch_bounds__(256) void k_prep(
    const float* __restrict__ Wk, const float* __restrict__ bk,
    const float* __restrict__ gamma, const float* __restrict__ beta,
    const float* __restrict__ Wv, const float* __restrict__ bv,
    const float* __restrict__ Wv2, const float* __restrict__ Ww,
    unsigned short* __restrict__ Wkv, float* __restrict__ bias2,
    unsigned short* __restrict__ Wv2b, unsigned short* __restrict__ Wwb)
{
    int idx = blockIdx.x * 256 + threadIdx.x;
    if (idx < 512 * 512) {
        int o = idx >> 9, c = idx & 511;
        float v;
        if (o < 256) { float s = gamma[o] * rsqrtf(1.f + BN_EPS); v = Wk[(size_t)o * 512 + c] * s; }
        else v = Wv[(size_t)(o - 256) * 512 + c];
        Wkv[idx] = f2bf(v);
        if (c == 0) {
            bias2[o] = (o < 256) ? (bk[o] * (gamma[o] * rsqrtf(1.f + BN_EPS)) + beta[o]) : bv[o - 256];
        }
    } else if (idx < 512 * 512 + 256 * 256) {
        int j = idx - 512 * 512;
        Wv2b[j] = f2bf(Wv2[j]);
    } else if (idx < 512 * 512 + 256 * 256 + 512 * 256) {
        int j = idx - 512 * 512 - 256 * 256;
        Wwb[j] = f2bf(Ww[j]);
    }
}

// ---------------- k_tx: x fp32 [b][c][n] -> xT bf16 [b][NPAD][512], pad rows zero ----------------
__global__ __launch_bounds__(256) void k_tx(const float* __restrict__ x,
                                            unsigned short* __restrict__ xT)
{
    int b = blockIdx.z;
    int n0 = blockIdx.x * 64;
    int c0 = blockIdx.y * 64;
    int tid = threadIdx.x;
    __shared__ float t[64][65];
    int j = tid & 63;
#pragma unroll
    for (int i = 0; i < 16; ++i) {
        int r = (tid >> 6) * 16 + i;
        int n = n0 + j;
        t[r][j] = (n < NN) ? x[((size_t)b * CINsz + c0 + r) * NN + n] : 0.f;
    }
    __syncthreads();
    int n_loc = tid >> 2;
    int cg = (tid & 3) * 16;
    us8 lo, hi;
    if (n0 + n_loc < NN) {
#pragma unroll
        for (int jj = 0; jj < 8; ++jj) { lo[jj] = f2bf(t[cg + jj][n_loc]); hi[jj] = f2bf(t[cg + 8 + jj][n_loc]); }
    } else {
#pragma unroll
        for (int jj = 0; jj < 8; ++jj) { lo[jj] = 0; hi[jj] = 0; }
    }
    unsigned short* dst = xT + ((size_t)b * NPAD + n0 + n_loc) * CINsz + c0 + cg;
    *reinterpret_cast<us8*>(dst) = lo;
    *reinterpret_cast<us8*>(dst + 8) = hi;
}

// ---------------- k_qkv: MFMA conv -> qkbf/value bf16 [b][n][256] ----------------
// block 256 = 4 waves: w0/w1 = qk (n0, n0+16), w2/w3 = value. grid (126, B).
__global__ __launch_bounds__(256) void k_qkv(const unsigned short* __restrict__ xT,
                                             const unsigned short* __restrict__ Wkv,
                                             const float* __restrict__ bias2,
                                             unsigned short* __restrict__ qkbf,
                                             unsigned short* __restrict__ value)
{
    int b = blockIdx.y;
    int nbase = blockIdx.x * 32;
    int tid = threadIdx.x, w = tid >> 6, lane = tid & 63, lg = lane >> 4, lr = lane & 15;
    int half = w >> 1;
    int n0 = nbase + (w & 1) * 16;
    int o_off = half * 256;
    const unsigned short* xrow = xT + ((size_t)b * NPAD + n0 + lr) * CINsz + lg * 8;
    const unsigned short* wbase = Wkv + (size_t)o_off * CINsz + lg * 8;

    f32x4 acc[16];
#pragma unroll
    for (int t = 0; t < 16; ++t) acc[t] = (f32x4){0.f, 0.f, 0.f, 0.f};
#pragma unroll
    for (int s = 0; s < 16; ++s) {
        bf16x8 af = *reinterpret_cast<const bf16x8*>(xrow + s * 32);
#pragma unroll
        for (int t = 0; t < 16; ++t) {
            bf16x8 bf = *reinterpret_cast<const bf16x8*>(wbase + (size_t)(t * 16 + lr) * CINsz + s * 32);
            acc[t] = MFMA16(af, bf, acc[t]);
        }
    }
    unsigned short* dst = (half == 0 ? qkbf : value) + (size_t)b * NPAD * CI;
#pragma unroll
    for (int t = 0; t < 16; ++t) {
        int o = t * 16 + lr;
        float bsum = bias2[o_off + o];
#pragma unroll
        for (int r = 0; r < 4; ++r) {
            int n = n0 + lg * 4 + r;
            dst[(size_t)n * CI + o] = f2bf(acc[t][r] + bsum);
        }
    }
}

// ---------------- k_pool: value bf16 [n][c] -> pooled bf16 [b][96][256] (pad rows zero) ----------
__global__ __launch_bounds__(256) void k_pool(const unsigned short* __restrict__ value,
                                              unsigned short* __restrict__ pooled)
{
    int b = blockIdx.y, k = blockIdx.x, c = threadIdx.x;
    unsigned short* dst = pooled + ((size_t)b * NKP + k) * CI + c;
    if (k >= NK) { *dst = 0; return; }
    int ky = k / 9, kx = k % 9;
    const unsigned short* vb = value + (size_t)b * NPAD * CI + c;
    float s = 0.f;
#pragma unroll
    for (int y = 0; y < 7; ++y)
#pragma unroll
        for (int xx = 0; xx < 7; ++xx) {
            int n = (ky * 7 + y) * HH + kx * 7 + xx;
            s += bf2f(vb[(size_t)n * CI]);
        }
    *dst = f2bf(s * (1.f / 49.f));
}

// ---------------- k_v2: D[k][o] = sum_c pooled[k][c]*Wv2b[o][c] + bv2 -> v2f bf16 [b][96][256] ---
__global__ __launch_bounds__(256) void k_v2(const unsigned short* __restrict__ pooled,
                                            const unsigned short* __restrict__ Wv2b,
                                            const float* __restrict__ bv2,
                                            unsigned short* __restrict__ v2f)
{
    int b = blockIdx.y;
    int tid = threadIdx.x, w = tid >> 6, lane = tid & 63, lg = lane >> 4, lr = lane & 15;
    int ot = blockIdx.x * 4 + w;       // 16 o-tiles
    const unsigned short* pb = pooled + (size_t)b * NKP * CI + lg * 8;
    const unsigned short* wb = Wv2b + (size_t)(ot * 16 + lr) * CI + lg * 8;
    f32x4 acc[6];
#pragma unroll
    for (int kt = 0; kt < 6; ++kt) acc[kt] = (f32x4){0.f, 0.f, 0.f, 0.f};
#pragma unroll
    for (int s = 0; s < 8; ++s) {
        bf16x8 bfw = *reinterpret_cast<const bf16x8*>(wb + s * 32);
#pragma unroll
        for (int kt = 0; kt < 6; ++kt) {
            bf16x8 af = *reinterpret_cast<const bf16x8*>(pb + (size_t)(kt * 16 + lr) * CI + s * 32);
            acc[kt] = MFMA16(af, bfw, acc[kt]);
        }
    }
    float bias = bv2[ot * 16 + lr];
#pragma unroll
    for (int kt = 0; kt < 6; ++kt)
#pragma unroll
        for (int r = 0; r < 4; ++r)
            v2f[((size_t)b * NKP + kt * 16 + lg * 4 + r) * CI + ot * 16 + lr] = f2bf(acc[kt][r] + bias);
}

// ---------------- k_Z: D[o][k] = sum_c Wwb[o][c]*v2f[k][c] -> Zt bf16 [b][512][96] ----------------
__global__ __launch_bounds__(256) void k_Z(const unsigned short* __restrict__ Wwb,
                                           const unsigned short* __restrict__ v2f,
                                           unsigned short* __restrict__ Zt)
{
    int b = blockIdx.y;
    int tid = threadIdx.x, w = tid >> 6, lane = tid & 63, lg = lane >> 4, lr = lane & 15;
    int ot = blockIdx.x * 4 + w;       // 32 o-tiles
    const unsigned short* wb = Wwb + (size_t)(ot * 16 + lr) * CI + lg * 8;
    const unsigned short* vb = v2f + (size_t)b * NKP * CI + lg * 8;
    f32x4 acc[6];
#pragma unroll
    for (int kt = 0; kt < 6; ++kt) acc[kt] = (f32x4){0.f, 0.f, 0.f, 0.f};
#pragma unroll
    for (int s = 0; s < 8; ++s) {
        bf16x8 af = *reinterpret_cast<const bf16x8*>(wb + s * 32);
#pragma unroll
        for (int kt = 0; kt < 6; ++kt) {
            bf16x8 bfv = *reinterpret_cast<const bf16x8*>(vb + (size_t)(kt * 16 + lr) * CI + s * 32);
            acc[kt] = MFMA16(af, bfv, acc[kt]);
        }
    }
#pragma unroll
    for (int kt = 0; kt < 6; ++kt)
#pragma unroll
        for (int r = 0; r < 4; ++r)
            Zt[((size_t)b * CO + ot * 16 + lg * 4 + r) * NKP + kt * 16 + lr] = f2bf(acc[kt][r]);
}

// ---------------- k_simv: D[n][k]=softmax_k(scale*value[n][c].v2f[k][c]) -> svT bf16 [b][96][NPAD]
__global__ __launch_bounds__(256) void k_simv(const unsigned short* __restrict__ value,
                                              const unsigned short* __restrict__ v2f,
                                              unsigned short* __restrict__ svT)
{
    int b = blockIdx.y;
    int tid = threadIdx.x, w = tid >> 6, lane = tid & 63, lg = lane >> 4, lr = lane & 15;
    int n0 = blockIdx.x * 64 + w * 16;
    const unsigned short* vrow = value + ((size_t)b * NPAD + n0 + lr) * CI + lg * 8;
    const unsigned short* v2b = v2f + (size_t)b * NKP * CI + lg * 8;
    f32x4 acc[6];
#pragma unroll
    for (int kt = 0; kt < 6; ++kt) acc[kt] = (f32x4){0.f, 0.f, 0.f, 0.f};
#pragma unroll
    for (int s = 0; s < 8; ++s) {
        bf16x8 af = *reinterpret_cast<const bf16x8*>(vrow + s * 32);
#pragma unroll
        for (int kt = 0; kt < 6; ++kt) {
            bf16x8 bfv = *reinterpret_cast<const bf16x8*>(v2b + (size_t)(kt * 16 + lr) * CI + s * 32);
            acc[kt] = MFMA16(af, bfv, acc[kt]);
        }
    }
#pragma unroll
    for (int kt = 0; kt < 6; ++kt) {
        bool bad = (kt * 16 + lr) >= NK;
#pragma unroll
        for (int r = 0; r < 4; ++r) acc[kt][r] = bad ? -1e30f : acc[kt][r] * SCALE;
    }
#pragma unroll
    for (int r = 0; r < 4; ++r) {
        float m = acc[0][r];
#pragma unroll
        for (int kt = 1; kt < 6; ++kt) m = fmaxf(m, acc[kt][r]);
#pragma unroll
        for (int off = 1; off < 16; off <<= 1) m = fmaxf(m, __shfl_xor(m, off));
        float p[6], sum = 0.f;
#pragma unroll
        for (int kt = 0; kt < 6; ++kt) { p[kt] = __expf(acc[kt][r] - m); sum += p[kt]; }
#pragma unroll
        for (int off = 1; off < 16; off <<= 1) sum += __shfl_xor(sum, off);
        float inv = 1.f / sum;
#pragma unroll
        for (int kt = 0; kt < 6; ++kt) acc[kt][r] = p[kt] * inv;
    }
#pragma unroll
    for (int kt = 0; kt < 6; ++kt) {
        us4 pk;
#pragma unroll
        for (int r = 0; r < 4; ++r) pk[r] = f2bf(acc[kt][r]);
        *reinterpret_cast<us4*>(&svT[((size_t)b * NKP + kt * 16 + lr) * NPAD + n0 + lg * 4]) = pk;
    }
}

// ---------------- k_flash: barrier-light, all fragments direct from L2 ----------------
// block 256 = 4 independent waves x 16 q-rows; grid (63, B).
__global__ __launch_bounds__(256, 1) void k_flash(const unsigned short* __restrict__ qkbf,
                                                  const unsigned short* __restrict__ svT,
                                                  unsigned short* __restrict__ simnew)
{
    int b = blockIdx.y;
    int tid = threadIdx.x, w = tid >> 6, lane = tid & 63, lg = lane >> 4, lr = lane & 15;
    int q0 = blockIdx.x * 64 + w * 16;
    __shared__ unsigned short p_all[4][16 * 64];
    unsigned short* pw = p_all[w];
    const unsigned short* qkb = qkbf + (size_t)b * NPAD * CI;
    const unsigned short* svb = svT + (size_t)b * NKP * NPAD;

    bf16x8 qa[8];
#pragma unroll
    for (int s = 0; s < 8; ++s)
        qa[s] = *reinterpret_cast<const bf16x8*>(qkb + (size_t)(q0 + lr) * CI + s * 32 + lg * 8);

    f32x4 acc[6];
#pragma unroll
    for (int jt = 0; jt < 6; ++jt) acc[jt] = (f32x4){0.f, 0.f, 0.f, 0.f};
    float m_run[4], l_run[4];
#pragma unroll
    for (int r = 0; r < 4; ++r) { m_run[r] = -1e30f; l_run[r] = 0.f; }

    for (int mb = 0; mb < 63; ++mb) {
        __syncthreads();   // pacing only: keep 4 waves on the same K tile for L1 reuse
        int mbase = mb * 64;
        f32x4 s_acc[4];
#pragma unroll
        for (int t = 0; t < 4; ++t) s_acc[t] = (f32x4){0.f, 0.f, 0.f, 0.f};
#pragma unroll
        for (int t = 0; t < 4; ++t) {
            const unsigned short* kr = qkb + (size_t)(mbase + t * 16 + lr) * CI + lg * 8;
#pragma unroll
            for (int s = 0; s < 8; ++s) {
                bf16x8 kf = *reinterpret_cast<const bf16x8*>(kr + s * 32);
                s_acc[t] = MFMA16(qa[s], kf, s_acc[t]);
            }
        }
#pragma unroll
        for (int t = 0; t < 4; ++t) {
            bool bad = (mbase + t * 16 + lr) >= NN;
#pragma unroll
            for (int r = 0; r < 4; ++r) s_acc[t][r] = bad ? -1e30f : s_acc[t][r] * SCALE;
        }
        float al[4];
#pragma unroll
        for (int r = 0; r < 4; ++r) {
            float m0 = fmaxf(fmaxf(s_acc[0][r], s_acc[1][r]), fmaxf(s_acc[2][r], s_acc[3][r]));
#pragma unroll
            for (int off = 1; off < 16; off <<= 1) m0 = fmaxf(m0, __shfl_xor(m0, off));
            float mn = fmaxf(m_run[r], m0);
            al[r] = __expf(m_run[r] - mn);
            m_run[r] = mn;
        }
        float psum[4] = {0.f, 0.f, 0.f, 0.f};
#pragma unroll
        for (int t = 0; t < 4; ++t) {
#pragma unroll
            for (int r = 0; r < 4; ++r) {
                float p = __expf(s_acc[t][r] - m_run[r]);
                psum[r] += p;
                int row = lg * 4 + r, col = t * 16 + lr;
                pw[row * 64 + (col ^ ((row & 7) << 3))] = f2bf(p);
            }
        }
#pragma unroll
        for (int r = 0; r < 4; ++r) {
            float ps = psum[r];
#pragma unroll
            for (int off = 1; off < 16; off <<= 1) ps += __shfl_xor(ps, off);
            l_run[r] = l_run[r] * al[r] + ps;
#pragma unroll
            for (int jt = 0; jt < 6; ++jt) acc[jt][r] *= al[r];
        }
#pragma unroll
        for (int kb = 0; kb < 2; ++kb) {
            int hw = kb * 32 + lg * 8;
            bf16x8 pa = *reinterpret_cast<const bf16x8*>(&pw[lr * 64 + (hw ^ ((lr & 7) << 3))]);
#pragma unroll
            for (int jt = 0; jt < 6; ++jt) {
                bf16x8 svf = *reinterpret_cast<const bf16x8*>(svb + (size_t)(jt * 16 + lr) * NPAD + mbase + hw);
                acc[jt] = MFMA16(pa, svf, acc[jt]);
            }
        }
    }
#pragma unroll
    for (int r = 0; r < 4; ++r) {
        float inv = 1.f / l_run[r];
        unsigned short* orow = simnew + ((size_t)b * NPAD + q0 + lg * 4 + r) * NKP;
#pragma unroll
        for (int jt = 0; jt < 6; ++jt)
            orow[jt * 16 + lr] = f2bf(acc[jt][r] * inv);
    }
}

// ---------------- k_out: D[o][n] = sum_k Zt[o][k]*simnew[n][k] + bw -> out fp32 [b][o][n] --------
__global__ __launch_bounds__(256) void k_out(const unsigned short* __restrict__ simnew,
                                             const unsigned short* __restrict__ Zt,
                                             const float* __restrict__ bw,
                                             float* __restrict__ out)
{
    int b = blockIdx.z;
    int ng = blockIdx.x, og = blockIdx.y;
    int tid = threadIdx.x, w = tid >> 6, lane = tid & 63, lg = lane >> 4, lr = lane & 15;
    int o_row = (og * 4 + w) * 16;
    const unsigned short* za = Zt + ((size_t)b * CO + o_row + lr) * NKP + lg * 8;
    bf16x8 az[3];
#pragma unroll
    for (int ks = 0; ks < 3; ++ks) az[ks] = *reinterpret_cast<const bf16x8*>(za + ks * 32);
    f32x4 acc[4];
#pragma unroll
    for (int jn = 0; jn < 4; ++jn) acc[jn] = (f32x4){0.f, 0.f, 0.f, 0.f};
    const unsigned short* sb = simnew + ((size_t)b * NPAD + ng * 64) * NKP + lg * 8;
#pragma unroll
    for (int jn = 0; jn < 4; ++jn)
#pragma unroll
        for (int ks = 0; ks < 3; ++ks) {
            bf16x8 bfs = *reinterpret_cast<const bf16x8*>(sb + (size_t)(jn * 16 + lr) * NKP + ks * 32);
            acc[jn] = MFMA16(az[ks], bfs, acc[jn]);
        }
#pragma unroll
    for (int r = 0; r < 4; ++r) {
        int o = o_row + lg * 4 + r;
        float bias = bw[o];
        float* orow = out + ((size_t)b * CO + o) * NN;
#pragma unroll
        for (int jn = 0; jn < 4; ++jn) {
            int n = ng * 64 + jn * 16 + lr;
            if (n < NN) orow[n] = acc[jn][r] + bias;
        }
    }
}

extern "C" void kernel_launch(void* const* d_in, const int* in_sizes, int n_in,
                              void* d_out, int out_size, void* d_ws, size_t ws_size,
                              hipStream_t stream)
{
    const float* x     = (const float*)d_in[0];
    const float* Wk    = (const float*)d_in[1];
    const float* bk    = (const float*)d_in[2];
    const float* gamma = (const float*)d_in[3];
    const float* beta  = (const float*)d_in[4];
    const float* Wv    = (const float*)d_in[5];
    const float* bv    = (const float*)d_in[6];
    const float* Wv2   = (const float*)d_in[7];
    const float* bv2   = (const float*)d_in[8];
    const float* Ww    = (const float*)d_in[9];
    const float* bw    = (const float*)d_in[10];
    float* out = (float*)d_out;

    char* p = (char*)d_ws;
    unsigned short* xT     = (unsigned short*)p; p += (size_t)BB * NPAD * CINsz * 2;
    unsigned short* qkbf   = (unsigned short*)p; p += (size_t)BB * NPAD * CI * 2;
    unsigned short* value  = (unsigned short*)p; p += (size_t)BB * NPAD * CI * 2;
    unsigned short* svT    = (unsigned short*)p; p += (size_t)BB * NKP * NPAD * 2;
    unsigned short* simnew = (unsigned short*)p; p += (size_t)BB * NPAD * NKP * 2;
    unsigned short* Wkv    = (unsigned short*)p; p += (size_t)512 * 512 * 2;
    unsigned short* Wv2b   = (unsigned short*)p; p += (size_t)256 * 256 * 2;
    unsigned short* Wwb    = (unsigned short*)p; p += (size_t)512 * 256 * 2;
    unsigned short* pooled = (unsigned short*)p; p += (size_t)BB * NKP * CI * 2;
    unsigned short* v2f    = (unsigned short*)p; p += (size_t)BB * NKP * CI * 2;
    unsigned short* Zt     = (unsigned short*)p; p += (size_t)BB * CO * NKP * 2;
    float* bias2           = (float*)p;          p += 512 * 4;

    k_prep<<<dim3(1794), 256, 0, stream>>>(Wk, bk, gamma, beta, Wv, bv, Wv2, Ww,
                                           Wkv, bias2, Wv2b, Wwb);
    k_tx<<<dim3(63, 8, BB), 256, 0, stream>>>(x, xT);
    k_qkv<<<dim3(126, BB), 256, 0, stream>>>(xT, Wkv, bias2, qkbf, value);
    k_pool<<<dim3(NKP, BB), 256, 0, stream>>>(value, pooled);
    k_v2<<<dim3(4, BB), 256, 0, stream>>>(pooled, Wv2b, bv2, v2f);
    k_Z<<<dim3(8, BB), 256, 0, stream>>>(Wwb, v2f, Zt);
    k_simv<<<dim3(63, BB), 256, 0, stream>>>(value, v2f, svT);
    k_flash<<<dim3(63, BB), 256, 0, stream>>>(qkbf, svT, simnew);
    k_out<<<dim3(63, 8, BB), 256, 0, stream>>>(simnew, Zt, bw, out);
}

// Round 5
// 451.260 us; speedup vs baseline: 8.5221x; 1.1171x over previous
//
#include <hip/hip_runtime.h>
#include <hip/hip_bf16.h>

#define BB 4
#define CINsz 512
#define HH 63
#define NN 3969          // 63*63
#define NPAD 4032        // 63*64
#define CI 256
#define CO 512
#define NK 81
#define NKP 96           // padded k-dim
#define SCALE 0.0625f    // 256^-0.5
#define BN_EPS 1e-5f

typedef __bf16 bf16x8 __attribute__((ext_vector_type(8)));
typedef float f32x4 __attribute__((ext_vector_type(4)));
typedef unsigned short us8 __attribute__((ext_vector_type(8)));
typedef unsigned short us4 __attribute__((ext_vector_type(4)));

#define MFMA16(a, b, c) __builtin_amdgcn_mfma_f32_16x16x32_bf16((a), (b), (c), 0, 0, 0)

__device__ inline unsigned short f2bf(float x) {
    union { float f; unsigned int u; } v; v.f = x;
    unsigned int r = v.u + 0x7FFF + ((v.u >> 16) & 1);
    return (unsigned short)(r >> 16);
}
__device__ inline float bf2f(unsigned short u) {
    union { unsigned int u; float f; } v; v.u = ((unsigned int)u) << 16;
    return v.f;
}

// ---------------- k_prep: weights -> bf16, BN folded into Wk ----------------
__global__ __launch_bounds__(256) void k_prep(
    const float* __restrict__ Wk, const float* __restrict__ bk,
    const float* __restrict__ gamma, const float* __restrict__ beta,
    const float* __restrict__ Wv, const float* __restrict__ bv,
    const float* __restrict__ Wv2, const float* __restrict__ Ww,
    unsigned short* __restrict__ Wkv, float* __restrict__ bias2,
    unsigned short* __restrict__ Wv2b, unsigned short* __restrict__ Wwb)
{
    int idx = blockIdx.x * 256 + threadIdx.x;
    if (idx < 512 * 512) {
        int o = idx >> 9, c = idx & 511;
        float v;
        if (o < 256) { float s = gamma[o] * rsqrtf(1.f + BN_EPS); v = Wk[(size_t)o * 512 + c] * s; }
        else v = Wv[(size_t)(o - 256) * 512 + c];
        Wkv[idx] = f2bf(v);
        if (c == 0) {
            bias2[o] = (o < 256) ? (bk[o] * (gamma[o] * rsqrtf(1.f + BN_EPS)) + beta[o]) : bv[o - 256];
        }
    } else if (idx < 512 * 512 + 256 * 256) {
        int j = idx - 512 * 512;
        Wv2b[j] = f2bf(Wv2[j]);
    } else if (idx < 512 * 512 + 256 * 256 + 512 * 256) {
        int j = idx - 512 * 512 - 256 * 256;
        Wwb[j] = f2bf(Ww[j]);
    }
}

// ---------------- k_tx: x fp32 [b][c][n] -> xT bf16 [b][NPAD][512], pad rows zero ----------------
__global__ __launch_bounds__(256) void k_tx(const float* __restrict__ x,
                                            unsigned short* __restrict__ xT)
{
    int b = blockIdx.z;
    int n0 = blockIdx.x * 64;
    int c0 = blockIdx.y * 64;
    int tid = threadIdx.x;
    __shared__ float t[64][65];
    int j = tid & 63;
#pragma unroll
    for (int i = 0; i < 16; ++i) {
        int r = (tid >> 6) * 16 + i;
        int n = n0 + j;
        t[r][j] = (n < NN) ? x[((size_t)b * CINsz + c0 + r) * NN + n] : 0.f;
    }
    __syncthreads();
    int n_loc = tid >> 2;
    int cg = (tid & 3) * 16;
    us8 lo, hi;
    if (n0 + n_loc < NN) {
#pragma unroll
        for (int jj = 0; jj < 8; ++jj) { lo[jj] = f2bf(t[cg + jj][n_loc]); hi[jj] = f2bf(t[cg + 8 + jj][n_loc]); }
    } else {
#pragma unroll
        for (int jj = 0; jj < 8; ++jj) { lo[jj] = 0; hi[jj] = 0; }
    }
    unsigned short* dst = xT + ((size_t)b * NPAD + n0 + n_loc) * CINsz + c0 + cg;
    *reinterpret_cast<us8*>(dst) = lo;
    *reinterpret_cast<us8*>(dst + 8) = hi;
}

// ---------------- k_qkv: MFMA conv -> qkbf/value bf16 [b][n][256] ----------------
__global__ __launch_bounds__(256) void k_qkv(const unsigned short* __restrict__ xT,
                                             const unsigned short* __restrict__ Wkv,
                                             const float* __restrict__ bias2,
                                             unsigned short* __restrict__ qkbf,
                                             unsigned short* __restrict__ value)
{
    int b = blockIdx.y;
    int nbase = blockIdx.x * 32;
    int tid = threadIdx.x, w = tid >> 6, lane = tid & 63, lg = lane >> 4, lr = lane & 15;
    int half = w >> 1;
    int n0 = nbase + (w & 1) * 16;
    int o_off = half * 256;
    const unsigned short* xrow = xT + ((size_t)b * NPAD + n0 + lr) * CINsz + lg * 8;
    const unsigned short* wbase = Wkv + (size_t)o_off * CINsz + lg * 8;

    f32x4 acc[16];
#pragma unroll
    for (int t = 0; t < 16; ++t) acc[t] = (f32x4){0.f, 0.f, 0.f, 0.f};
#pragma unroll
    for (int s = 0; s < 16; ++s) {
        bf16x8 af = *reinterpret_cast<const bf16x8*>(xrow + s * 32);
#pragma unroll
        for (int t = 0; t < 16; ++t) {
            bf16x8 bf = *reinterpret_cast<const bf16x8*>(wbase + (size_t)(t * 16 + lr) * CINsz + s * 32);
            acc[t] = MFMA16(af, bf, acc[t]);
        }
    }
    unsigned short* dst = (half == 0 ? qkbf : value) + (size_t)b * NPAD * CI;
#pragma unroll
    for (int t = 0; t < 16; ++t) {
        int o = t * 16 + lr;
        float bsum = bias2[o_off + o];
#pragma unroll
        for (int r = 0; r < 4; ++r) {
            int n = n0 + lg * 4 + r;
            dst[(size_t)n * CI + o] = f2bf(acc[t][r] + bsum);
        }
    }
}

// ---------------- k_pool ----------------
__global__ __launch_bounds__(256) void k_pool(const unsigned short* __restrict__ value,
                                              unsigned short* __restrict__ pooled)
{
    int b = blockIdx.y, k = blockIdx.x, c = threadIdx.x;
    unsigned short* dst = pooled + ((size_t)b * NKP + k) * CI + c;
    if (k >= NK) { *dst = 0; return; }
    int ky = k / 9, kx = k % 9;
    const unsigned short* vb = value + (size_t)b * NPAD * CI + c;
    float s = 0.f;
#pragma unroll
    for (int y = 0; y < 7; ++y)
#pragma unroll
        for (int xx = 0; xx < 7; ++xx) {
            int n = (ky * 7 + y) * HH + kx * 7 + xx;
            s += bf2f(vb[(size_t)n * CI]);
        }
    *dst = f2bf(s * (1.f / 49.f));
}

// ---------------- k_v2 ----------------
__global__ __launch_bounds__(256) void k_v2(const unsigned short* __restrict__ pooled,
                                            const unsigned short* __restrict__ Wv2b,
                                            const float* __restrict__ bv2,
                                            unsigned short* __restrict__ v2f)
{
    int b = blockIdx.y;
    int tid = threadIdx.x, w = tid >> 6, lane = tid & 63, lg = lane >> 4, lr = lane & 15;
    int ot = blockIdx.x * 4 + w;
    const unsigned short* pb = pooled + (size_t)b * NKP * CI + lg * 8;
    const unsigned short* wb = Wv2b + (size_t)(ot * 16 + lr) * CI + lg * 8;
    f32x4 acc[6];
#pragma unroll
    for (int kt = 0; kt < 6; ++kt) acc[kt] = (f32x4){0.f, 0.f, 0.f, 0.f};
#pragma unroll
    for (int s = 0; s < 8; ++s) {
        bf16x8 bfw = *reinterpret_cast<const bf16x8*>(wb + s * 32);
#pragma unroll
        for (int kt = 0; kt < 6; ++kt) {
            bf16x8 af = *reinterpret_cast<const bf16x8*>(pb + (size_t)(kt * 16 + lr) * CI + s * 32);
            acc[kt] = MFMA16(af, bfw, acc[kt]);
        }
    }
    float bias = bv2[ot * 16 + lr];
#pragma unroll
    for (int kt = 0; kt < 6; ++kt)
#pragma unroll
        for (int r = 0; r < 4; ++r)
            v2f[((size_t)b * NKP + kt * 16 + lg * 4 + r) * CI + ot * 16 + lr] = f2bf(acc[kt][r] + bias);
}

// ---------------- k_Z ----------------
__global__ __launch_bounds__(256) void k_Z(const unsigned short* __restrict__ Wwb,
                                           const unsigned short* __restrict__ v2f,
                                           unsigned short* __restrict__ Zt)
{
    int b = blockIdx.y;
    int tid = threadIdx.x, w = tid >> 6, lane = tid & 63, lg = lane >> 4, lr = lane & 15;
    int ot = blockIdx.x * 4 + w;
    const unsigned short* wb = Wwb + (size_t)(ot * 16 + lr) * CI + lg * 8;
    const unsigned short* vb = v2f + (size_t)b * NKP * CI + lg * 8;
    f32x4 acc[6];
#pragma unroll
    for (int kt = 0; kt < 6; ++kt) acc[kt] = (f32x4){0.f, 0.f, 0.f, 0.f};
#pragma unroll
    for (int s = 0; s < 8; ++s) {
        bf16x8 af = *reinterpret_cast<const bf16x8*>(wb + s * 32);
#pragma unroll
        for (int kt = 0; kt < 6; ++kt) {
            bf16x8 bfv = *reinterpret_cast<const bf16x8*>(vb + (size_t)(kt * 16 + lr) * CI + s * 32);
            acc[kt] = MFMA16(af, bfv, acc[kt]);
        }
    }
#pragma unroll
    for (int kt = 0; kt < 6; ++kt)
#pragma unroll
        for (int r = 0; r < 4; ++r)
            Zt[((size_t)b * CO + ot * 16 + lg * 4 + r) * NKP + kt * 16 + lr] = f2bf(acc[kt][r]);
}

// ---------------- k_simv ----------------
__global__ __launch_bounds__(256) void k_simv(const unsigned short* __restrict__ value,
                                              const unsigned short* __restrict__ v2f,
                                              unsigned short* __restrict__ svT)
{
    int b = blockIdx.y;
    int tid = threadIdx.x, w = tid >> 6, lane = tid & 63, lg = lane >> 4, lr = lane & 15;
    int n0 = blockIdx.x * 64 + w * 16;
    const unsigned short* vrow = value + ((size_t)b * NPAD + n0 + lr) * CI + lg * 8;
    const unsigned short* v2b = v2f + (size_t)b * NKP * CI + lg * 8;
    f32x4 acc[6];
#pragma unroll
    for (int kt = 0; kt < 6; ++kt) acc[kt] = (f32x4){0.f, 0.f, 0.f, 0.f};
#pragma unroll
    for (int s = 0; s < 8; ++s) {
        bf16x8 af = *reinterpret_cast<const bf16x8*>(vrow + s * 32);
#pragma unroll
        for (int kt = 0; kt < 6; ++kt) {
            bf16x8 bfv = *reinterpret_cast<const bf16x8*>(v2b + (size_t)(kt * 16 + lr) * CI + s * 32);
            acc[kt] = MFMA16(af, bfv, acc[kt]);
        }
    }
#pragma unroll
    for (int kt = 0; kt < 6; ++kt) {
        bool bad = (kt * 16 + lr) >= NK;
#pragma unroll
        for (int r = 0; r < 4; ++r) acc[kt][r] = bad ? -1e30f : acc[kt][r] * SCALE;
    }
#pragma unroll
    for (int r = 0; r < 4; ++r) {
        float m = acc[0][r];
#pragma unroll
        for (int kt = 1; kt < 6; ++kt) m = fmaxf(m, acc[kt][r]);
#pragma unroll
        for (int off = 1; off < 16; off <<= 1) m = fmaxf(m, __shfl_xor(m, off));
        float p[6], sum = 0.f;
#pragma unroll
        for (int kt = 0; kt < 6; ++kt) { p[kt] = __expf(acc[kt][r] - m); sum += p[kt]; }
#pragma unroll
        for (int off = 1; off < 16; off <<= 1) sum += __shfl_xor(sum, off);
        float inv = 1.f / sum;
#pragma unroll
        for (int kt = 0; kt < 6; ++kt) acc[kt][r] = p[kt] * inv;
    }
#pragma unroll
    for (int kt = 0; kt < 6; ++kt) {
        us4 pk;
#pragma unroll
        for (int r = 0; r < 4; ++r) pk[r] = f2bf(acc[kt][r]);
        *reinterpret_cast<us4*>(&svT[((size_t)b * NKP + kt * 16 + lr) * NPAD + n0 + lg * 4]) = pk;
    }
}

// ---------------- k_flash: split-KV flash. Block = 16 q-rows, 4 waves each own ~16 kv-tiles ----
// grid 1008 1D: batch = bid&3 (XCD-local under %8 round-robin), qg = bid>>2.
__global__ __launch_bounds__(256, 4) void k_flash(const unsigned short* __restrict__ qkbf,
                                                  const unsigned short* __restrict__ svT,
                                                  unsigned short* __restrict__ simnew)
{
    int bid = blockIdx.x;
    int b = bid & 3;
    int q0 = (bid >> 2) * 16;
    int tid = threadIdx.x, w = tid >> 6, lane = tid & 63, lg = lane >> 4, lr = lane & 15;
    __shared__ unsigned short p_all[4][16 * 64];
    __shared__ float macc[4][64][25];
    __shared__ float mml[4][16];
    __shared__ float lml[4][16];
    unsigned short* pw = p_all[w];
    const unsigned short* qkb = qkbf + (size_t)b * NPAD * CI;
    const unsigned short* svb = svT + (size_t)b * NKP * NPAD;

    bf16x8 qa[8];
#pragma unroll
    for (int s = 0; s < 8; ++s)
        qa[s] = *reinterpret_cast<const bf16x8*>(qkb + (size_t)(q0 + lr) * CI + s * 32 + lg * 8);

    f32x4 acc[6];
#pragma unroll
    for (int jt = 0; jt < 6; ++jt) acc[jt] = (f32x4){0.f, 0.f, 0.f, 0.f};
    float m_run[4], l_run[4];
#pragma unroll
    for (int r = 0; r < 4; ++r) { m_run[r] = -1e30f; l_run[r] = 0.f; }

    int mb_lo = w * 16;
    int mb_hi = mb_lo + 16 > 63 ? 63 : mb_lo + 16;
    for (int mb = mb_lo; mb < mb_hi; ++mb) {
        int mbase = mb * 64;
        f32x4 s_acc[4];
#pragma unroll
        for (int t = 0; t < 4; ++t) s_acc[t] = (f32x4){0.f, 0.f, 0.f, 0.f};
        const unsigned short* kr0 = qkb + (size_t)(mbase + lr) * CI + lg * 8;
#pragma unroll
        for (int s = 0; s < 8; ++s) {
            bf16x8 kf[4];
#pragma unroll
            for (int t = 0; t < 4; ++t)
                kf[t] = *reinterpret_cast<const bf16x8*>(kr0 + (size_t)(t * 16) * CI + s * 32);
#pragma unroll
            for (int t = 0; t < 4; ++t)
                s_acc[t] = MFMA16(qa[s], kf[t], s_acc[t]);
        }
#pragma unroll
        for (int t = 0; t < 4; ++t) {
            bool bad = (mbase + t * 16 + lr) >= NN;
#pragma unroll
            for (int r = 0; r < 4; ++r) s_acc[t][r] = bad ? -1e30f : s_acc[t][r] * SCALE;
        }
        float al[4];
#pragma unroll
        for (int r = 0; r < 4; ++r) {
            float m0 = fmaxf(fmaxf(s_acc[0][r], s_acc[1][r]), fmaxf(s_acc[2][r], s_acc[3][r]));
#pragma unroll
            for (int off = 1; off < 16; off <<= 1) m0 = fmaxf(m0, __shfl_xor(m0, off));
            float mn = fmaxf(m_run[r], m0);
            al[r] = __expf(m_run[r] - mn);
            m_run[r] = mn;
        }
        float psum[4] = {0.f, 0.f, 0.f, 0.f};
#pragma unroll
        for (int t = 0; t < 4; ++t) {
#pragma unroll
            for (int r = 0; r < 4; ++r) {
                float p = __expf(s_acc[t][r] - m_run[r]);
                psum[r] += p;
                int row = lg * 4 + r, col = t * 16 + lr;
                pw[row * 64 + (col ^ ((row & 7) << 3))] = f2bf(p);
            }
        }
#pragma unroll
        for (int r = 0; r < 4; ++r) {
            float ps = psum[r];
#pragma unroll
            for (int off = 1; off < 16; off <<= 1) ps += __shfl_xor(ps, off);
            l_run[r] = l_run[r] * al[r] + ps;
#pragma unroll
            for (int jt = 0; jt < 6; ++jt) acc[jt][r] *= al[r];
        }
#pragma unroll
        for (int kb = 0; kb < 2; ++kb) {
            int hw = kb * 32 + lg * 8;
            bf16x8 pa = *reinterpret_cast<const bf16x8*>(&pw[lr * 64 + (hw ^ ((lr & 7) << 3))]);
#pragma unroll
            for (int jt = 0; jt < 6; ++jt) {
                bf16x8 svf = *reinterpret_cast<const bf16x8*>(svb + (size_t)(jt * 16 + lr) * NPAD + mbase + hw);
                acc[jt] = MFMA16(pa, svf, acc[jt]);
            }
        }
    }
    // ---- write partials and merge
#pragma unroll
    for (int jt = 0; jt < 6; ++jt)
#pragma unroll
        for (int r = 0; r < 4; ++r) macc[w][lane][jt * 4 + r] = acc[jt][r];
    if (lr == 0) {
#pragma unroll
        for (int r = 0; r < 4; ++r) { mml[w][lg * 4 + r] = m_run[r]; lml[w][lg * 4 + r] = l_run[r]; }
    }
    __syncthreads();
    if (w == 0) {
        float f[4][4], inv[4];
#pragma unroll
        for (int r = 0; r < 4; ++r) {
            int row = lg * 4 + r;
            float mg = fmaxf(fmaxf(mml[0][row], mml[1][row]), fmaxf(mml[2][row], mml[3][row]));
            float ls = 0.f;
#pragma unroll
            for (int ww = 0; ww < 4; ++ww) {
                f[ww][r] = __expf(mml[ww][row] - mg);
                ls += f[ww][r] * lml[ww][row];
            }
            inv[r] = 1.f / ls;
        }
#pragma unroll
        for (int r = 0; r < 4; ++r) {
            unsigned short* orow = simnew + ((size_t)b * NPAD + q0 + lg * 4 + r) * NKP;
#pragma unroll
            for (int jt = 0; jt < 6; ++jt) {
                float a = 0.f;
#pragma unroll
                for (int ww = 0; ww < 4; ++ww) a += macc[ww][lane][jt * 4 + r] * f[ww][r];
                orow[jt * 16 + lr] = f2bf(a * inv[r]);
            }
        }
    }
}

// ---------------- k_out ----------------
__global__ __launch_bounds__(256) void k_out(const unsigned short* __restrict__ simnew,
                                             const unsigned short* __restrict__ Zt,
                                             const float* __restrict__ bw,
                                             float* __restrict__ out)
{
    int b = blockIdx.z;
    int ng = blockIdx.x, og = blockIdx.y;
    int tid = threadIdx.x, w = tid >> 6, lane = tid & 63, lg = lane >> 4, lr = lane & 15;
    int o_row = (og * 4 + w) * 16;
    const unsigned short* za = Zt + ((size_t)b * CO + o_row + lr) * NKP + lg * 8;
    bf16x8 az[3];
#pragma unroll
    for (int ks = 0; ks < 3; ++ks) az[ks] = *reinterpret_cast<const bf16x8*>(za + ks * 32);
    f32x4 acc[4];
#pragma unroll
    for (int jn = 0; jn < 4; ++jn) acc[jn] = (f32x4){0.f, 0.f, 0.f, 0.f};
    const unsigned short* sb = simnew + ((size_t)b * NPAD + ng * 64) * NKP + lg * 8;
#pragma unroll
    for (int jn = 0; jn < 4; ++jn)
#pragma unroll
        for (int ks = 0; ks < 3; ++ks) {
            bf16x8 bfs = *reinterpret_cast<const bf16x8*>(sb + (size_t)(jn * 16 + lr) * NKP + ks * 32);
            acc[jn] = MFMA16(az[ks], bfs, acc[jn]);
        }
#pragma unroll
    for (int r = 0; r < 4; ++r) {
        int o = o_row + lg * 4 + r;
        float bias = bw[o];
        float* orow = out + ((size_t)b * CO + o) * NN;
#pragma unroll
        for (int jn = 0; jn < 4; ++jn) {
            int n = ng * 64 + jn * 16 + lr;
            if (n < NN) orow[n] = acc[jn][r] + bias;
        }
    }
}

extern "C" void kernel_launch(void* const* d_in, const int* in_sizes, int n_in,
                              void* d_out, int out_size, void* d_ws, size_t ws_size,
                              hipStream_t stream)
{
    const float* x     = (const float*)d_in[0];
    const float* Wk    = (const float*)d_in[1];
    const float* bk    = (const float*)d_in[2];
    const float* gamma = (const float*)d_in[3];
    const float* beta  = (const float*)d_in[4];
    const float* Wv    = (const float*)d_in[5];
    const float* bv    = (const float*)d_in[6];
    const float* Wv2   = (const float*)d_in[7];
    const float* bv2   = (const float*)d_in[8];
    const float* Ww    = (const float*)d_in[9];
    const float* bw    = (const float*)d_in[10];
    float* out = (float*)d_out;

    char* p = (char*)d_ws;
    unsigned short* xT     = (unsigned short*)p; p += (size_t)BB * NPAD * CINsz * 2;
    unsigned short* qkbf   = (unsigned short*)p; p += (size_t)BB * NPAD * CI * 2;
    unsigned short* value  = (unsigned short*)p; p += (size_t)BB * NPAD * CI * 2;
    unsigned short* svT    = (unsigned short*)p; p += (size_t)BB * NKP * NPAD * 2;
    unsigned short* simnew = (unsigned short*)p; p += (size_t)BB * NPAD * NKP * 2;
    unsigned short* Wkv    = (unsigned short*)p; p += (size_t)512 * 512 * 2;
    unsigned short* Wv2b   = (unsigned short*)p; p += (size_t)256 * 256 * 2;
    unsigned short* Wwb    = (unsigned short*)p; p += (size_t)512 * 256 * 2;
    unsigned short* pooled = (unsigned short*)p; p += (size_t)BB * NKP * CI * 2;
    unsigned short* v2f    = (unsigned short*)p; p += (size_t)BB * NKP * CI * 2;
    unsigned short* Zt     = (unsigned short*)p; p += (size_t)BB * CO * NKP * 2;
    float* bias2           = (float*)p;          p += 512 * 4;

    k_prep<<<dim3(1794), 256, 0, stream>>>(Wk, bk, gamma, beta, Wv, bv, Wv2, Ww,
                                           Wkv, bias2, Wv2b, Wwb);
    k_tx<<<dim3(63, 8, BB), 256, 0, stream>>>(x, xT);
    k_qkv<<<dim3(126, BB), 256, 0, stream>>>(xT, Wkv, bias2, qkbf, value);
    k_pool<<<dim3(NKP, BB), 256, 0, stream>>>(value, pooled);
    k_v2<<<dim3(4, BB), 256, 0, stream>>>(pooled, Wv2b, bv2, v2f);
    k_Z<<<dim3(8, BB), 256, 0, stream>>>(Wwb, v2f, Zt);
    k_simv<<<dim3(63, BB), 256, 0, stream>>>(value, v2f, svT);
    k_flash<<<dim3(1008), 256, 0, stream>>>(qkbf, svT, simnew);
    k_out<<<dim3(63, 8, BB), 256, 0, stream>>>(simnew, Zt, bw, out);
}

// Round 6
// 284.763 us; speedup vs baseline: 13.5048x; 1.5847x over previous
//
#include <hip/hip_runtime.h>
#include <hip/hip_bf16.h>

#define BB 4
#define CINsz 512
#define HH 63
#define NN 3969          // 63*63
#define NPAD 4032        // 63*64
#define CI 256
#define CO 512
#define NK 81
#define NKP 96           // padded k-dim
#define SCALE 0.0625f    // 256^-0.5
#define BN_EPS 1e-5f

typedef __bf16 bf16x8 __attribute__((ext_vector_type(8)));
typedef float f32x4 __attribute__((ext_vector_type(4)));
typedef unsigned short us8 __attribute__((ext_vector_type(8)));
typedef unsigned short us4 __attribute__((ext_vector_type(4)));

#define MFMA16(a, b, c) __builtin_amdgcn_mfma_f32_16x16x32_bf16((a), (b), (c), 0, 0, 0)

__device__ inline unsigned short f2bf(float x) {
    union { float f; unsigned int u; } v; v.f = x;
    unsigned int r = v.u + 0x7FFF + ((v.u >> 16) & 1);
    return (unsigned short)(r >> 16);
}
__device__ inline float bf2f(unsigned short u) {
    union { unsigned int u; float f; } v; v.u = ((unsigned int)u) << 16;
    return v.f;
}

// async global->LDS, 16B per lane, linear LDS dest (wave-uniform base + lane*16)
__device__ inline void gll16(const void* g, void* l) {
    __builtin_amdgcn_global_load_lds(
        (const __attribute__((address_space(1))) unsigned int*)g,
        (__attribute__((address_space(3))) unsigned int*)l, 16, 0, 0);
}

// ---------------- k_prep: weights -> bf16, BN folded into Wk ----------------
__global__ __launch_bounds__(256) void k_prep(
    const float* __restrict__ Wk, const float* __restrict__ bk,
    const float* __restrict__ gamma, const float* __restrict__ beta,
    const float* __restrict__ Wv, const float* __restrict__ bv,
    const float* __restrict__ Wv2, const float* __restrict__ Ww,
    unsigned short* __restrict__ Wkv, float* __restrict__ bias2,
    unsigned short* __restrict__ Wv2b, unsigned short* __restrict__ Wwb)
{
    int idx = blockIdx.x * 256 + threadIdx.x;
    if (idx < 512 * 512) {
        int o = idx >> 9, c = idx & 511;
        float v;
        if (o < 256) { float s = gamma[o] * rsqrtf(1.f + BN_EPS); v = Wk[(size_t)o * 512 + c] * s; }
        else v = Wv[(size_t)(o - 256) * 512 + c];
        Wkv[idx] = f2bf(v);
        if (c == 0) {
            bias2[o] = (o < 256) ? (bk[o] * (gamma[o] * rsqrtf(1.f + BN_EPS)) + beta[o]) : bv[o - 256];
        }
    } else if (idx < 512 * 512 + 256 * 256) {
        int j = idx - 512 * 512;
        Wv2b[j] = f2bf(Wv2[j]);
    } else if (idx < 512 * 512 + 256 * 256 + 512 * 256) {
        int j = idx - 512 * 512 - 256 * 256;
        Wwb[j] = f2bf(Ww[j]);
    }
}

// ---------------- k_tx: x fp32 [b][c][n] -> xT bf16 [b][NPAD][512], pad rows zero ----------------
__global__ __launch_bounds__(256) void k_tx(const float* __restrict__ x,
                                            unsigned short* __restrict__ xT)
{
    int b = blockIdx.z;
    int n0 = blockIdx.x * 64;
    int c0 = blockIdx.y * 64;
    int tid = threadIdx.x;
    __shared__ float t[64][65];
    int j = tid & 63;
#pragma unroll
    for (int i = 0; i < 16; ++i) {
        int r = (tid >> 6) * 16 + i;
        int n = n0 + j;
        t[r][j] = (n < NN) ? x[((size_t)b * CINsz + c0 + r) * NN + n] : 0.f;
    }
    __syncthreads();
    int n_loc = tid >> 2;
    int cg = (tid & 3) * 16;
    us8 lo, hi;
    if (n0 + n_loc < NN) {
#pragma unroll
        for (int jj = 0; jj < 8; ++jj) { lo[jj] = f2bf(t[cg + jj][n_loc]); hi[jj] = f2bf(t[cg + 8 + jj][n_loc]); }
    } else {
#pragma unroll
        for (int jj = 0; jj < 8; ++jj) { lo[jj] = 0; hi[jj] = 0; }
    }
    unsigned short* dst = xT + ((size_t)b * NPAD + n0 + n_loc) * CINsz + c0 + cg;
    *reinterpret_cast<us8*>(dst) = lo;
    *reinterpret_cast<us8*>(dst + 8) = hi;
}

// ---------------- k_qkv: MFMA conv -> qkbf/value bf16 [b][n][256] ----------------
__global__ __launch_bounds__(256) void k_qkv(const unsigned short* __restrict__ xT,
                                             const unsigned short* __restrict__ Wkv,
                                             const float* __restrict__ bias2,
                                             unsigned short* __restrict__ qkbf,
                                             unsigned short* __restrict__ value)
{
    int b = blockIdx.y;
    int nbase = blockIdx.x * 32;
    int tid = threadIdx.x, w = tid >> 6, lane = tid & 63, lg = lane >> 4, lr = lane & 15;
    int half = w >> 1;
    int n0 = nbase + (w & 1) * 16;
    int o_off = half * 256;
    const unsigned short* xrow = xT + ((size_t)b * NPAD + n0 + lr) * CINsz + lg * 8;
    const unsigned short* wbase = Wkv + (size_t)o_off * CINsz + lg * 8;

    f32x4 acc[16];
#pragma unroll
    for (int t = 0; t < 16; ++t) acc[t] = (f32x4){0.f, 0.f, 0.f, 0.f};
#pragma unroll
    for (int s = 0; s < 16; ++s) {
        bf16x8 af = *reinterpret_cast<const bf16x8*>(xrow + s * 32);
#pragma unroll
        for (int t = 0; t < 16; ++t) {
            bf16x8 bf = *reinterpret_cast<const bf16x8*>(wbase + (size_t)(t * 16 + lr) * CINsz + s * 32);
            acc[t] = MFMA16(af, bf, acc[t]);
        }
    }
    unsigned short* dst = (half == 0 ? qkbf : value) + (size_t)b * NPAD * CI;
#pragma unroll
    for (int t = 0; t < 16; ++t) {
        int o = t * 16 + lr;
        float bsum = bias2[o_off + o];
#pragma unroll
        for (int r = 0; r < 4; ++r) {
            int n = n0 + lg * 4 + r;
            dst[(size_t)n * CI + o] = f2bf(acc[t][r] + bsum);
        }
    }
}

// ---------------- k_pool ----------------
__global__ __launch_bounds__(256) void k_pool(const unsigned short* __restrict__ value,
                                              unsigned short* __restrict__ pooled)
{
    int b = blockIdx.y, k = blockIdx.x, c = threadIdx.x;
    unsigned short* dst = pooled + ((size_t)b * NKP + k) * CI + c;
    if (k >= NK) { *dst = 0; return; }
    int ky = k / 9, kx = k % 9;
    const unsigned short* vb = value + (size_t)b * NPAD * CI + c;
    float s = 0.f;
#pragma unroll
    for (int y = 0; y < 7; ++y)
#pragma unroll
        for (int xx = 0; xx < 7; ++xx) {
            int n = (ky * 7 + y) * HH + kx * 7 + xx;
            s += bf2f(vb[(size_t)n * CI]);
        }
    *dst = f2bf(s * (1.f / 49.f));
}

// ---------------- k_v2 ----------------
__global__ __launch_bounds__(256) void k_v2(const unsigned short* __restrict__ pooled,
                                            const unsigned short* __restrict__ Wv2b,
                                            const float* __restrict__ bv2,
                                            unsigned short* __restrict__ v2f)
{
    int b = blockIdx.y;
    int tid = threadIdx.x, w = tid >> 6, lane = tid & 63, lg = lane >> 4, lr = lane & 15;
    int ot = blockIdx.x * 4 + w;
    const unsigned short* pb = pooled + (size_t)b * NKP * CI + lg * 8;
    const unsigned short* wb = Wv2b + (size_t)(ot * 16 + lr) * CI + lg * 8;
    f32x4 acc[6];
#pragma unroll
    for (int kt = 0; kt < 6; ++kt) acc[kt] = (f32x4){0.f, 0.f, 0.f, 0.f};
#pragma unroll
    for (int s = 0; s < 8; ++s) {
        bf16x8 bfw = *reinterpret_cast<const bf16x8*>(wb + s * 32);
#pragma unroll
        for (int kt = 0; kt < 6; ++kt) {
            bf16x8 af = *reinterpret_cast<const bf16x8*>(pb + (size_t)(kt * 16 + lr) * CI + s * 32);
            acc[kt] = MFMA16(af, bfw, acc[kt]);
        }
    }
    float bias = bv2[ot * 16 + lr];
#pragma unroll
    for (int kt = 0; kt < 6; ++kt)
#pragma unroll
        for (int r = 0; r < 4; ++r)
            v2f[((size_t)b * NKP + kt * 16 + lg * 4 + r) * CI + ot * 16 + lr] = f2bf(acc[kt][r] + bias);
}

// ---------------- k_Z ----------------
__global__ __launch_bounds__(256) void k_Z(const unsigned short* __restrict__ Wwb,
                                           const unsigned short* __restrict__ v2f,
                                           unsigned short* __restrict__ Zt)
{
    int b = blockIdx.y;
    int tid = threadIdx.x, w = tid >> 6, lane = tid & 63, lg = lane >> 4, lr = lane & 15;
    int ot = blockIdx.x * 4 + w;
    const unsigned short* wb = Wwb + (size_t)(ot * 16 + lr) * CI + lg * 8;
    const unsigned short* vb = v2f + (size_t)b * NKP * CI + lg * 8;
    f32x4 acc[6];
#pragma unroll
    for (int kt = 0; kt < 6; ++kt) acc[kt] = (f32x4){0.f, 0.f, 0.f, 0.f};
#pragma unroll
    for (int s = 0; s < 8; ++s) {
        bf16x8 af = *reinterpret_cast<const bf16x8*>(wb + s * 32);
#pragma unroll
        for (int kt = 0; kt < 6; ++kt) {
            bf16x8 bfv = *reinterpret_cast<const bf16x8*>(vb + (size_t)(kt * 16 + lr) * CI + s * 32);
            acc[kt] = MFMA16(af, bfv, acc[kt]);
        }
    }
#pragma unroll
    for (int kt = 0; kt < 6; ++kt)
#pragma unroll
        for (int r = 0; r < 4; ++r)
            Zt[((size_t)b * CO + ot * 16 + lg * 4 + r) * NKP + kt * 16 + lr] = f2bf(acc[kt][r]);
}

// ---------------- k_simv ----------------
__global__ __launch_bounds__(256) void k_simv(const unsigned short* __restrict__ value,
                                              const unsigned short* __restrict__ v2f,
                                              unsigned short* __restrict__ svT)
{
    int b = blockIdx.y;
    int tid = threadIdx.x, w = tid >> 6, lane = tid & 63, lg = lane >> 4, lr = lane & 15;
    int n0 = blockIdx.x * 64 + w * 16;
    const unsigned short* vrow = value + ((size_t)b * NPAD + n0 + lr) * CI + lg * 8;
    const unsigned short* v2b = v2f + (size_t)b * NKP * CI + lg * 8;
    f32x4 acc[6];
#pragma unroll
    for (int kt = 0; kt < 6; ++kt) acc[kt] = (f32x4){0.f, 0.f, 0.f, 0.f};
#pragma unroll
    for (int s = 0; s < 8; ++s) {
        bf16x8 af = *reinterpret_cast<const bf16x8*>(vrow + s * 32);
#pragma unroll
        for (int kt = 0; kt < 6; ++kt) {
            bf16x8 bfv = *reinterpret_cast<const bf16x8*>(v2b + (size_t)(kt * 16 + lr) * CI + s * 32);
            acc[kt] = MFMA16(af, bfv, acc[kt]);
        }
    }
#pragma unroll
    for (int kt = 0; kt < 6; ++kt) {
        bool bad = (kt * 16 + lr) >= NK;
#pragma unroll
        for (int r = 0; r < 4; ++r) acc[kt][r] = bad ? -1e30f : acc[kt][r] * SCALE;
    }
#pragma unroll
    for (int r = 0; r < 4; ++r) {
        float m = acc[0][r];
#pragma unroll
        for (int kt = 1; kt < 6; ++kt) m = fmaxf(m, acc[kt][r]);
#pragma unroll
        for (int off = 1; off < 16; off <<= 1) m = fmaxf(m, __shfl_xor(m, off));
        float p[6], sum = 0.f;
#pragma unroll
        for (int kt = 0; kt < 6; ++kt) { p[kt] = __expf(acc[kt][r] - m); sum += p[kt]; }
#pragma unroll
        for (int off = 1; off < 16; off <<= 1) sum += __shfl_xor(sum, off);
        float inv = 1.f / sum;
#pragma unroll
        for (int kt = 0; kt < 6; ++kt) acc[kt][r] = p[kt] * inv;
    }
#pragma unroll
    for (int kt = 0; kt < 6; ++kt) {
        us4 pk;
#pragma unroll
        for (int r = 0; r < 4; ++r) pk[r] = f2bf(acc[kt][r]);
        *reinterpret_cast<us4*>(&svT[((size_t)b * NKP + kt * 16 + lr) * NPAD + n0 + lg * 4]) = pk;
    }
}

// ---------------- k_flash: shared-KV, async LDS double-buffer (T3 2-phase) ----------------
// Block = 64 q-rows (4 waves x 16), kv tile 64 keys, 63 iters. grid 252 linear, b = bid&3.
// K tile LDS [64][256hw] and SV tile [96][64hw], both XOR-swizzled via pre-swizzled global src.
__global__ __launch_bounds__(256) void k_flash(const unsigned short* __restrict__ qkbf,
                                               const unsigned short* __restrict__ svT,
                                               unsigned short* __restrict__ simnew)
{
    int bid = blockIdx.x;
    int b = bid & 3;
    int tid = threadIdx.x, w = tid >> 6, lane = tid & 63, lg = lane >> 4, lr = lane & 15;
    int q0 = (bid >> 2) * 64 + w * 16;

    __shared__ unsigned short k_lds[2][64 * 256];   // 32KB each
    __shared__ unsigned short sv_lds[2][96 * 64];   // 12KB each
    __shared__ unsigned short p_all[4][16 * 64];    // 2KB each

    const unsigned short* qkb = qkbf + (size_t)b * NPAD * CI;
    const unsigned short* svb = svT + (size_t)b * NKP * NPAD;
    unsigned short* pw = p_all[w];

    // Q fragments in registers
    bf16x8 qa[8];
#pragma unroll
    for (int s = 0; s < 8; ++s)
        qa[s] = *reinterpret_cast<const bf16x8*>(qkb + (size_t)(q0 + lr) * CI + s * 32 + lg * 8);

    f32x4 acc[6];
#pragma unroll
    for (int jt = 0; jt < 6; ++jt) acc[jt] = (f32x4){0.f, 0.f, 0.f, 0.f};
    float m_run[4], l_run[4];
#pragma unroll
    for (int r = 0; r < 4; ++r) { m_run[r] = -1e30f; l_run[r] = 0.f; }

    // ---- async stage of one kv tile (wave w's share), pre-swizzled global source
    auto stage = [&](int mbase, int bi) {
        // K: 8 chunks x 1KB (2 rows of 512B each); rows w*16 .. w*16+15
#pragma unroll
        for (int j = 0; j < 8; ++j) {
            int r = w * 16 + j * 2 + (lane >> 5);
            int c_hw = ((lane & 31) * 8) ^ ((r & 7) << 3);
            gll16(qkb + (size_t)(mbase + r) * CI + c_hw,
                  &k_lds[bi][(w * 16 + j * 2) * 256]);
        }
        // SV: 3 chunks x 1KB (8 rows of 128B each); rows w*24 .. w*24+23
#pragma unroll
        for (int j = 0; j < 3; ++j) {
            int k = w * 24 + j * 8 + (lane >> 3);
            int m_hw = ((lane & 7) * 8) ^ ((k & 7) << 3);
            gll16(svb + (size_t)k * NPAD + mbase + m_hw,
                  &sv_lds[bi][(w * 24 + j * 8) * 64]);
        }
    };

    stage(0, 0);
    __syncthreads();   // drains vmcnt -> tile 0 resident

    for (int mb = 0; mb < 63; ++mb) {
        int bi = mb & 1;
        int mbase = mb * 64;
        if (mb < 62) stage(mbase + 64, bi ^ 1);   // prefetch next tile (overlaps compute)

        // ---- QK^T from LDS
        f32x4 s_acc[4];
#pragma unroll
        for (int t = 0; t < 4; ++t) s_acc[t] = (f32x4){0.f, 0.f, 0.f, 0.f};
#pragma unroll
        for (int s = 0; s < 8; ++s) {
#pragma unroll
            for (int t = 0; t < 4; ++t) {
                int row = t * 16 + lr;
                int hw = (s * 32 + lg * 8) ^ ((row & 7) << 3);
                bf16x8 kf = *reinterpret_cast<const bf16x8*>(&k_lds[bi][row * 256 + hw]);
                s_acc[t] = MFMA16(qa[s], kf, s_acc[t]);
            }
        }
#pragma unroll
        for (int t = 0; t < 4; ++t) {
            bool bad = (mbase + t * 16 + lr) >= NN;
#pragma unroll
            for (int r = 0; r < 4; ++r) s_acc[t][r] = bad ? -1e30f : s_acc[t][r] * SCALE;
        }
        // ---- online softmax
        float al[4];
#pragma unroll
        for (int r = 0; r < 4; ++r) {
            float m0 = fmaxf(fmaxf(s_acc[0][r], s_acc[1][r]), fmaxf(s_acc[2][r], s_acc[3][r]));
#pragma unroll
            for (int off = 1; off < 16; off <<= 1) m0 = fmaxf(m0, __shfl_xor(m0, off));
            float mn = fmaxf(m_run[r], m0);
            al[r] = __expf(m_run[r] - mn);
            m_run[r] = mn;
        }
        float psum[4] = {0.f, 0.f, 0.f, 0.f};
#pragma unroll
        for (int t = 0; t < 4; ++t) {
#pragma unroll
            for (int r = 0; r < 4; ++r) {
                float p = __expf(s_acc[t][r] - m_run[r]);
                psum[r] += p;
                int row = lg * 4 + r, col = t * 16 + lr;
                pw[row * 64 + (col ^ ((row & 7) << 3))] = f2bf(p);
            }
        }
#pragma unroll
        for (int r = 0; r < 4; ++r) {
            float ps = psum[r];
#pragma unroll
            for (int off = 1; off < 16; off <<= 1) ps += __shfl_xor(ps, off);
            l_run[r] = l_run[r] * al[r] + ps;
#pragma unroll
            for (int jt = 0; jt < 6; ++jt) acc[jt][r] *= al[r];
        }
        // ---- PV from LDS
#pragma unroll
        for (int kb = 0; kb < 2; ++kb) {
            int hw = kb * 32 + lg * 8;
            bf16x8 pa = *reinterpret_cast<const bf16x8*>(&pw[lr * 64 + (hw ^ ((lr & 7) << 3))]);
#pragma unroll
            for (int jt = 0; jt < 6; ++jt) {
                int cr = jt * 16 + lr;
                bf16x8 svf = *reinterpret_cast<const bf16x8*>(
                    &sv_lds[bi][cr * 64 + (hw ^ ((cr & 7) << 3))]);
                acc[jt] = MFMA16(pa, svf, acc[jt]);
            }
        }
        __syncthreads();   // drains vmcnt (prefetch done) + all waves done reading buffers
    }
    // ---- epilogue
#pragma unroll
    for (int r = 0; r < 4; ++r) {
        float inv = 1.f / l_run[r];
        unsigned short* orow = simnew + ((size_t)b * NPAD + q0 + lg * 4 + r) * NKP;
#pragma unroll
        for (int jt = 0; jt < 6; ++jt)
            orow[jt * 16 + lr] = f2bf(acc[jt][r] * inv);
    }
}

// ---------------- k_out ----------------
__global__ __launch_bounds__(256) void k_out(const unsigned short* __restrict__ simnew,
                                             const unsigned short* __restrict__ Zt,
                                             const float* __restrict__ bw,
                                             float* __restrict__ out)
{
    int b = blockIdx.z;
    int ng = blockIdx.x, og = blockIdx.y;
    int tid = threadIdx.x, w = tid >> 6, lane = tid & 63, lg = lane >> 4, lr = lane & 15;
    int o_row = (og * 4 + w) * 16;
    const unsigned short* za = Zt + ((size_t)b * CO + o_row + lr) * NKP + lg * 8;
    bf16x8 az[3];
#pragma unroll
    for (int ks = 0; ks < 3; ++ks) az[ks] = *reinterpret_cast<const bf16x8*>(za + ks * 32);
    f32x4 acc[4];
#pragma unroll
    for (int jn = 0; jn < 4; ++jn) acc[jn] = (f32x4){0.f, 0.f, 0.f, 0.f};
    const unsigned short* sb = simnew + ((size_t)b * NPAD + ng * 64) * NKP + lg * 8;
#pragma unroll
    for (int jn = 0; jn < 4; ++jn)
#pragma unroll
        for (int ks = 0; ks < 3; ++ks) {
            bf16x8 bfs = *reinterpret_cast<const bf16x8*>(sb + (size_t)(jn * 16 + lr) * NKP + ks * 32);
            acc[jn] = MFMA16(az[ks], bfs, acc[jn]);
        }
#pragma unroll
    for (int r = 0; r < 4; ++r) {
        int o = o_row + lg * 4 + r;
        float bias = bw[o];
        float* orow = out + ((size_t)b * CO + o) * NN;
#pragma unroll
        for (int jn = 0; jn < 4; ++jn) {
            int n = ng * 64 + jn * 16 + lr;
            if (n < NN) orow[n] = acc[jn][r] + bias;
        }
    }
}

extern "C" void kernel_launch(void* const* d_in, const int* in_sizes, int n_in,
                              void* d_out, int out_size, void* d_ws, size_t ws_size,
                              hipStream_t stream)
{
    const float* x     = (const float*)d_in[0];
    const float* Wk    = (const float*)d_in[1];
    const float* bk    = (const float*)d_in[2];
    const float* gamma = (const float*)d_in[3];
    const float* beta  = (const float*)d_in[4];
    const float* Wv    = (const float*)d_in[5];
    const float* bv    = (const float*)d_in[6];
    const float* Wv2   = (const float*)d_in[7];
    const float* bv2   = (const float*)d_in[8];
    const float* Ww    = (const float*)d_in[9];
    const float* bw    = (const float*)d_in[10];
    float* out = (float*)d_out;

    char* p = (char*)d_ws;
    unsigned short* xT     = (unsigned short*)p; p += (size_t)BB * NPAD * CINsz * 2;
    unsigned short* qkbf   = (unsigned short*)p; p += (size_t)BB * NPAD * CI * 2;
    unsigned short* value  = (unsigned short*)p; p += (size_t)BB * NPAD * CI * 2;
    unsigned short* svT    = (unsigned short*)p; p += (size_t)BB * NKP * NPAD * 2;
    unsigned short* simnew = (unsigned short*)p; p += (size_t)BB * NPAD * NKP * 2;
    unsigned short* Wkv    = (unsigned short*)p; p += (size_t)512 * 512 * 2;
    unsigned short* Wv2b   = (unsigned short*)p; p += (size_t)256 * 256 * 2;
    unsigned short* Wwb    = (unsigned short*)p; p += (size_t)512 * 256 * 2;
    unsigned short* pooled = (unsigned short*)p; p += (size_t)BB * NKP * CI * 2;
    unsigned short* v2f    = (unsigned short*)p; p += (size_t)BB * NKP * CI * 2;
    unsigned short* Zt     = (unsigned short*)p; p += (size_t)BB * CO * NKP * 2;
    float* bias2           = (float*)p;          p += 512 * 4;

    k_prep<<<dim3(1794), 256, 0, stream>>>(Wk, bk, gamma, beta, Wv, bv, Wv2, Ww,
                                           Wkv, bias2, Wv2b, Wwb);
    k_tx<<<dim3(63, 8, BB), 256, 0, stream>>>(x, xT);
    k_qkv<<<dim3(126, BB), 256, 0, stream>>>(xT, Wkv, bias2, qkbf, value);
    k_pool<<<dim3(NKP, BB), 256, 0, stream>>>(value, pooled);
    k_v2<<<dim3(4, BB), 256, 0, stream>>>(pooled, Wv2b, bv2, v2f);
    k_Z<<<dim3(8, BB), 256, 0, stream>>>(Wwb, v2f, Zt);
    k_simv<<<dim3(63, BB), 256, 0, stream>>>(value, v2f, svT);
    k_flash<<<dim3(252), 256, 0, stream>>>(qkbf, svT, simnew);
    k_out<<<dim3(63, 8, BB), 256, 0, stream>>>(simnew, Zt, bw, out);
}

// Round 7
// 251.929 us; speedup vs baseline: 15.2649x; 1.1303x over previous
//
#include <hip/hip_runtime.h>
#include <hip/hip_bf16.h>

#define BB 4
#define CINsz 512
#define HH 63
#define NN 3969          // 63*63
#define NPAD 4032        // 63*64
#define CI 256
#define CO 512
#define NK 81
#define NKP 96           // padded k-dim
#define SCALE 0.0625f    // 256^-0.5
#define BN_EPS 1e-5f

typedef __bf16 bf16x8 __attribute__((ext_vector_type(8)));
typedef float f32x4 __attribute__((ext_vector_type(4)));
typedef unsigned short us8 __attribute__((ext_vector_type(8)));
typedef unsigned short us4 __attribute__((ext_vector_type(4)));

#define MFMA16(a, b, c) __builtin_amdgcn_mfma_f32_16x16x32_bf16((a), (b), (c), 0, 0, 0)

__device__ inline unsigned short f2bf(float x) {
    union { float f; unsigned int u; } v; v.f = x;
    unsigned int r = v.u + 0x7FFF + ((v.u >> 16) & 1);
    return (unsigned short)(r >> 16);
}
__device__ inline float bf2f(unsigned short u) {
    union { unsigned int u; float f; } v; v.u = ((unsigned int)u) << 16;
    return v.f;
}

// async global->LDS, 16B per lane, linear LDS dest (wave-uniform base + lane*16)
__device__ inline void gll16(const void* g, void* l) {
    __builtin_amdgcn_global_load_lds(
        (const __attribute__((address_space(1))) unsigned int*)g,
        (__attribute__((address_space(3))) unsigned int*)l, 16, 0, 0);
}

// ---------------- k_prep: weights -> bf16, BN folded into Wk ----------------
__global__ __launch_bounds__(256) void k_prep(
    const float* __restrict__ Wk, const float* __restrict__ bk,
    const float* __restrict__ gamma, const float* __restrict__ beta,
    const float* __restrict__ Wv, const float* __restrict__ bv,
    const float* __restrict__ Wv2, const float* __restrict__ Ww,
    unsigned short* __restrict__ Wkv, float* __restrict__ bias2,
    unsigned short* __restrict__ Wv2b, unsigned short* __restrict__ Wwb)
{
    int idx = blockIdx.x * 256 + threadIdx.x;
    if (idx < 512 * 512) {
        int o = idx >> 9, c = idx & 511;
        float v;
        if (o < 256) { float s = gamma[o] * rsqrtf(1.f + BN_EPS); v = Wk[(size_t)o * 512 + c] * s; }
        else v = Wv[(size_t)(o - 256) * 512 + c];
        Wkv[idx] = f2bf(v);
        if (c == 0) {
            bias2[o] = (o < 256) ? (bk[o] * (gamma[o] * rsqrtf(1.f + BN_EPS)) + beta[o]) : bv[o - 256];
        }
    } else if (idx < 512 * 512 + 256 * 256) {
        int j = idx - 512 * 512;
        Wv2b[j] = f2bf(Wv2[j]);
    } else if (idx < 512 * 512 + 256 * 256 + 512 * 256) {
        int j = idx - 512 * 512 - 256 * 256;
        Wwb[j] = f2bf(Ww[j]);
    }
}

// ---------------- k_tx: x fp32 [b][c][n] -> xT bf16 [b][NPAD][512], pad rows zero ----------------
__global__ __launch_bounds__(256) void k_tx(const float* __restrict__ x,
                                            unsigned short* __restrict__ xT)
{
    int b = blockIdx.z;
    int n0 = blockIdx.x * 64;
    int c0 = blockIdx.y * 64;
    int tid = threadIdx.x;
    __shared__ float t[64][65];
    int j = tid & 63;
#pragma unroll
    for (int i = 0; i < 16; ++i) {
        int r = (tid >> 6) * 16 + i;
        int n = n0 + j;
        t[r][j] = (n < NN) ? x[((size_t)b * CINsz + c0 + r) * NN + n] : 0.f;
    }
    __syncthreads();
    int n_loc = tid >> 2;
    int cg = (tid & 3) * 16;
    us8 lo, hi;
    if (n0 + n_loc < NN) {
#pragma unroll
        for (int jj = 0; jj < 8; ++jj) { lo[jj] = f2bf(t[cg + jj][n_loc]); hi[jj] = f2bf(t[cg + 8 + jj][n_loc]); }
    } else {
#pragma unroll
        for (int jj = 0; jj < 8; ++jj) { lo[jj] = 0; hi[jj] = 0; }
    }
    unsigned short* dst = xT + ((size_t)b * NPAD + n0 + n_loc) * CINsz + c0 + cg;
    *reinterpret_cast<us8*>(dst) = lo;
    *reinterpret_cast<us8*>(dst + 8) = hi;
}

// ---------------- k_qkv: MFMA conv -> qkbf/value bf16 [b][n][256] ----------------
__global__ __launch_bounds__(256) void k_qkv(const unsigned short* __restrict__ xT,
                                             const unsigned short* __restrict__ Wkv,
                                             const float* __restrict__ bias2,
                                             unsigned short* __restrict__ qkbf,
                                             unsigned short* __restrict__ value)
{
    int b = blockIdx.y;
    int nbase = blockIdx.x * 32;
    int tid = threadIdx.x, w = tid >> 6, lane = tid & 63, lg = lane >> 4, lr = lane & 15;
    int half = w >> 1;
    int n0 = nbase + (w & 1) * 16;
    int o_off = half * 256;
    const unsigned short* xrow = xT + ((size_t)b * NPAD + n0 + lr) * CINsz + lg * 8;
    const unsigned short* wbase = Wkv + (size_t)o_off * CINsz + lg * 8;

    f32x4 acc[16];
#pragma unroll
    for (int t = 0; t < 16; ++t) acc[t] = (f32x4){0.f, 0.f, 0.f, 0.f};
#pragma unroll
    for (int s = 0; s < 16; ++s) {
        bf16x8 af = *reinterpret_cast<const bf16x8*>(xrow + s * 32);
#pragma unroll
        for (int t = 0; t < 16; ++t) {
            bf16x8 bf = *reinterpret_cast<const bf16x8*>(wbase + (size_t)(t * 16 + lr) * CINsz + s * 32);
            acc[t] = MFMA16(af, bf, acc[t]);
        }
    }
    unsigned short* dst = (half == 0 ? qkbf : value) + (size_t)b * NPAD * CI;
#pragma unroll
    for (int t = 0; t < 16; ++t) {
        int o = t * 16 + lr;
        float bsum = bias2[o_off + o];
#pragma unroll
        for (int r = 0; r < 4; ++r) {
            int n = n0 + lg * 4 + r;
            dst[(size_t)n * CI + o] = f2bf(acc[t][r] + bsum);
        }
    }
}

// ---------------- k_pool ----------------
__global__ __launch_bounds__(256) void k_pool(const unsigned short* __restrict__ value,
                                              unsigned short* __restrict__ pooled)
{
    int b = blockIdx.y, k = blockIdx.x, c = threadIdx.x;
    unsigned short* dst = pooled + ((size_t)b * NKP + k) * CI + c;
    if (k >= NK) { *dst = 0; return; }
    int ky = k / 9, kx = k % 9;
    const unsigned short* vb = value + (size_t)b * NPAD * CI + c;
    float s = 0.f;
#pragma unroll
    for (int y = 0; y < 7; ++y)
#pragma unroll
        for (int xx = 0; xx < 7; ++xx) {
            int n = (ky * 7 + y) * HH + kx * 7 + xx;
            s += bf2f(vb[(size_t)n * CI]);
        }
    *dst = f2bf(s * (1.f / 49.f));
}

// ---------------- k_v2 ----------------
__global__ __launch_bounds__(256) void k_v2(const unsigned short* __restrict__ pooled,
                                            const unsigned short* __restrict__ Wv2b,
                                            const float* __restrict__ bv2,
                                            unsigned short* __restrict__ v2f)
{
    int b = blockIdx.y;
    int tid = threadIdx.x, w = tid >> 6, lane = tid & 63, lg = lane >> 4, lr = lane & 15;
    int ot = blockIdx.x * 4 + w;
    const unsigned short* pb = pooled + (size_t)b * NKP * CI + lg * 8;
    const unsigned short* wb = Wv2b + (size_t)(ot * 16 + lr) * CI + lg * 8;
    f32x4 acc[6];
#pragma unroll
    for (int kt = 0; kt < 6; ++kt) acc[kt] = (f32x4){0.f, 0.f, 0.f, 0.f};
#pragma unroll
    for (int s = 0; s < 8; ++s) {
        bf16x8 bfw = *reinterpret_cast<const bf16x8*>(wb + s * 32);
#pragma unroll
        for (int kt = 0; kt < 6; ++kt) {
            bf16x8 af = *reinterpret_cast<const bf16x8*>(pb + (size_t)(kt * 16 + lr) * CI + s * 32);
            acc[kt] = MFMA16(af, bfw, acc[kt]);
        }
    }
    float bias = bv2[ot * 16 + lr];
#pragma unroll
    for (int kt = 0; kt < 6; ++kt)
#pragma unroll
        for (int r = 0; r < 4; ++r)
            v2f[((size_t)b * NKP + kt * 16 + lg * 4 + r) * CI + ot * 16 + lr] = f2bf(acc[kt][r] + bias);
}

// ---------------- k_Z ----------------
__global__ __launch_bounds__(256) void k_Z(const unsigned short* __restrict__ Wwb,
                                           const unsigned short* __restrict__ v2f,
                                           unsigned short* __restrict__ Zt)
{
    int b = blockIdx.y;
    int tid = threadIdx.x, w = tid >> 6, lane = tid & 63, lg = lane >> 4, lr = lane & 15;
    int ot = blockIdx.x * 4 + w;
    const unsigned short* wb = Wwb + (size_t)(ot * 16 + lr) * CI + lg * 8;
    const unsigned short* vb = v2f + (size_t)b * NKP * CI + lg * 8;
    f32x4 acc[6];
#pragma unroll
    for (int kt = 0; kt < 6; ++kt) acc[kt] = (f32x4){0.f, 0.f, 0.f, 0.f};
#pragma unroll
    for (int s = 0; s < 8; ++s) {
        bf16x8 af = *reinterpret_cast<const bf16x8*>(wb + s * 32);
#pragma unroll
        for (int kt = 0; kt < 6; ++kt) {
            bf16x8 bfv = *reinterpret_cast<const bf16x8*>(vb + (size_t)(kt * 16 + lr) * CI + s * 32);
            acc[kt] = MFMA16(af, bfv, acc[kt]);
        }
    }
#pragma unroll
    for (int kt = 0; kt < 6; ++kt)
#pragma unroll
        for (int r = 0; r < 4; ++r)
            Zt[((size_t)b * CO + ot * 16 + lg * 4 + r) * NKP + kt * 16 + lr] = f2bf(acc[kt][r]);
}

// ---------------- k_simv ----------------
__global__ __launch_bounds__(256) void k_simv(const unsigned short* __restrict__ value,
                                              const unsigned short* __restrict__ v2f,
                                              unsigned short* __restrict__ svT)
{
    int b = blockIdx.y;
    int tid = threadIdx.x, w = tid >> 6, lane = tid & 63, lg = lane >> 4, lr = lane & 15;
    int n0 = blockIdx.x * 64 + w * 16;
    const unsigned short* vrow = value + ((size_t)b * NPAD + n0 + lr) * CI + lg * 8;
    const unsigned short* v2b = v2f + (size_t)b * NKP * CI + lg * 8;
    f32x4 acc[6];
#pragma unroll
    for (int kt = 0; kt < 6; ++kt) acc[kt] = (f32x4){0.f, 0.f, 0.f, 0.f};
#pragma unroll
    for (int s = 0; s < 8; ++s) {
        bf16x8 af = *reinterpret_cast<const bf16x8*>(vrow + s * 32);
#pragma unroll
        for (int kt = 0; kt < 6; ++kt) {
            bf16x8 bfv = *reinterpret_cast<const bf16x8*>(v2b + (size_t)(kt * 16 + lr) * CI + s * 32);
            acc[kt] = MFMA16(af, bfv, acc[kt]);
        }
    }
#pragma unroll
    for (int kt = 0; kt < 6; ++kt) {
        bool bad = (kt * 16 + lr) >= NK;
#pragma unroll
        for (int r = 0; r < 4; ++r) acc[kt][r] = bad ? -1e30f : acc[kt][r] * SCALE;
    }
#pragma unroll
    for (int r = 0; r < 4; ++r) {
        float m = acc[0][r];
#pragma unroll
        for (int kt = 1; kt < 6; ++kt) m = fmaxf(m, acc[kt][r]);
#pragma unroll
        for (int off = 1; off < 16; off <<= 1) m = fmaxf(m, __shfl_xor(m, off));
        float p[6], sum = 0.f;
#pragma unroll
        for (int kt = 0; kt < 6; ++kt) { p[kt] = __expf(acc[kt][r] - m); sum += p[kt]; }
#pragma unroll
        for (int off = 1; off < 16; off <<= 1) sum += __shfl_xor(sum, off);
        float inv = 1.f / sum;
#pragma unroll
        for (int kt = 0; kt < 6; ++kt) acc[kt][r] = p[kt] * inv;
    }
#pragma unroll
    for (int kt = 0; kt < 6; ++kt) {
        us4 pk;
#pragma unroll
        for (int r = 0; r < 4; ++r) pk[r] = f2bf(acc[kt][r]);
        *reinterpret_cast<us4*>(&svT[((size_t)b * NKP + kt * 16 + lr) * NPAD + n0 + lg * 4]) = pk;
    }
}

// ---------------- k_flash: 2-way split-KV, LDS dbuf K + single SV, P in idle K half ----------
// 76KB LDS -> 2 blocks/CU. grid 504: b=bid&3, qg=(bid>>2)%63, s=(bid>>2)/63.
// Writes fp32 partials (acc24, m, l) to part[(s*4+b)][col 0..97][NPAD].
__global__ __launch_bounds__(256) void k_flash(const unsigned short* __restrict__ qkbf,
                                               const unsigned short* __restrict__ svT,
                                               float* __restrict__ part)
{
    int bid = blockIdx.x;
    int b = bid & 3;
    int rest = bid >> 2;
    int qg = rest % 63;
    int s_id = rest / 63;              // 0 or 1
    int lo = s_id ? 32 : 0, hi = s_id ? 63 : 32;
    int tid = threadIdx.x, w = tid >> 6, lane = tid & 63, lg = lane >> 4, lr = lane & 15;
    int q0 = qg * 64 + w * 16;

    __shared__ unsigned short k_lds[2][64 * 256];   // 32KB each (rows 0-15 of current buf reused as P)
    __shared__ unsigned short sv_lds[96 * 64];      // 12KB single

    const unsigned short* qkb = qkbf + (size_t)b * NPAD * CI;
    const unsigned short* svb = svT + (size_t)b * NKP * NPAD;

    bf16x8 qa[8];
#pragma unroll
    for (int s = 0; s < 8; ++s)
        qa[s] = *reinterpret_cast<const bf16x8*>(qkb + (size_t)(q0 + lr) * CI + s * 32 + lg * 8);

    f32x4 acc[6];
#pragma unroll
    for (int jt = 0; jt < 6; ++jt) acc[jt] = (f32x4){0.f, 0.f, 0.f, 0.f};
    float m_run[4], l_run[4];
#pragma unroll
    for (int r = 0; r < 4; ++r) { m_run[r] = -1e30f; l_run[r] = 0.f; }

    auto stageK = [&](int t, int bi) {
#pragma unroll
        for (int j = 0; j < 8; ++j) {
            int r = w * 16 + j * 2 + (lane >> 5);
            int c_hw = ((lane & 31) * 8) ^ ((r & 7) << 3);
            gll16(qkb + (size_t)(t * 64 + r) * CI + c_hw,
                  &k_lds[bi][(w * 16 + j * 2) * 256]);
        }
    };
    auto stageSV = [&](int t) {
#pragma unroll
        for (int j = 0; j < 3; ++j) {
            int k = w * 24 + j * 8 + (lane >> 3);
            int m_hw = ((lane & 7) * 8) ^ ((k & 7) << 3);
            gll16(svb + (size_t)k * NPAD + t * 64 + m_hw,
                  &sv_lds[(w * 24 + j * 8) * 64]);
        }
    };

    stageK(lo, 0);
    stageSV(lo);
    __syncthreads();

    for (int t = lo; t < hi; ++t) {
        int bi = (t - lo) & 1;
        int mbase = t * 64;
        if (t + 1 < hi) stageK(t + 1, bi ^ 1);   // prefetch next K (other buffer)

        // ---- QK^T from k_lds[bi]
        f32x4 s_acc[4];
#pragma unroll
        for (int tt = 0; tt < 4; ++tt) s_acc[tt] = (f32x4){0.f, 0.f, 0.f, 0.f};
#pragma unroll
        for (int s = 0; s < 8; ++s) {
#pragma unroll
            for (int tt = 0; tt < 4; ++tt) {
                int row = tt * 16 + lr;
                int hw = (s * 32 + lg * 8) ^ ((row & 7) << 3);
                bf16x8 kf = *reinterpret_cast<const bf16x8*>(&k_lds[bi][row * 256 + hw]);
                s_acc[tt] = MFMA16(qa[s], kf, s_acc[tt]);
            }
        }
        __syncthreads();   // bar1: all waves done reading k_lds[bi]; K prefetch drained

        // ---- mask + online softmax
#pragma unroll
        for (int tt = 0; tt < 4; ++tt) {
            bool bad = (mbase + tt * 16 + lr) >= NN;
#pragma unroll
            for (int r = 0; r < 4; ++r) s_acc[tt][r] = bad ? -1e30f : s_acc[tt][r] * SCALE;
        }
        float al[4];
#pragma unroll
        for (int r = 0; r < 4; ++r) {
            float m0 = fmaxf(fmaxf(s_acc[0][r], s_acc[1][r]), fmaxf(s_acc[2][r], s_acc[3][r]));
#pragma unroll
            for (int off = 1; off < 16; off <<= 1) m0 = fmaxf(m0, __shfl_xor(m0, off));
            float mn = fmaxf(m_run[r], m0);
            al[r] = __expf(m_run[r] - mn);
            m_run[r] = mn;
        }
        // P into idle rows 0-15 of k_lds[bi] (wave-private 2KB slice)
        unsigned short* pw = &k_lds[bi][w * 1024];
        float psum[4] = {0.f, 0.f, 0.f, 0.f};
#pragma unroll
        for (int tt = 0; tt < 4; ++tt) {
#pragma unroll
            for (int r = 0; r < 4; ++r) {
                float p = __expf(s_acc[tt][r] - m_run[r]);
                psum[r] += p;
                int row = lg * 4 + r, col = tt * 16 + lr;
                pw[row * 64 + (col ^ ((row & 7) << 3))] = f2bf(p);
            }
        }
#pragma unroll
        for (int r = 0; r < 4; ++r) {
            float ps = psum[r];
#pragma unroll
            for (int off = 1; off < 16; off <<= 1) ps += __shfl_xor(ps, off);
            l_run[r] = l_run[r] * al[r] + ps;
#pragma unroll
            for (int jt = 0; jt < 6; ++jt) acc[jt][r] *= al[r];
        }
        // ---- PV from sv_lds (single buffer)
#pragma unroll
        for (int kb = 0; kb < 2; ++kb) {
            int hw = kb * 32 + lg * 8;
            bf16x8 pa = *reinterpret_cast<const bf16x8*>(&pw[lr * 64 + (hw ^ ((lr & 7) << 3))]);
#pragma unroll
            for (int jt = 0; jt < 6; ++jt) {
                int cr = jt * 16 + lr;
                bf16x8 svf = *reinterpret_cast<const bf16x8*>(
                    &sv_lds[cr * 64 + (hw ^ ((cr & 7) << 3))]);
                acc[jt] = MFMA16(pa, svf, acc[jt]);
            }
        }
        __syncthreads();   // bar2: all waves done with sv_lds + P
        if (t + 1 < hi) stageSV(t + 1);   // lands during next QK^T
    }
    // ---- write fp32 partials (no l-division; k_comb merges)
    float* pp = part + (size_t)(s_id * 4 + b) * 98 * NPAD;
#pragma unroll
    for (int r = 0; r < 4; ++r) {
        int row = q0 + lg * 4 + r;
#pragma unroll
        for (int jt = 0; jt < 6; ++jt)
            pp[(size_t)(jt * 16 + lr) * NPAD + row] = acc[jt][r];
        if (lr == 0) {
            pp[(size_t)96 * NPAD + row] = m_run[r];
            pp[(size_t)97 * NPAD + row] = l_run[r];
        }
    }
}

// ---------------- k_comb: merge 2 KV-split partials -> simnew bf16 [b][n][96] ----------------
__global__ __launch_bounds__(256) void k_comb(const float* __restrict__ part,
                                              unsigned short* __restrict__ simnew)
{
    int t = blockIdx.x * 256 + threadIdx.x;
    if (t >= 4 * NPAD) return;
    int b = t / NPAD, row = t - b * NPAD;
    const float* p0 = part + ((size_t)(0 * 4 + b) * 98) * NPAD + row;
    const float* p1 = part + ((size_t)(1 * 4 + b) * 98) * NPAD + row;
    float m0 = p0[(size_t)96 * NPAD], l0 = p0[(size_t)97 * NPAD];
    float m1 = p1[(size_t)96 * NPAD], l1 = p1[(size_t)97 * NPAD];
    float mg = fmaxf(m0, m1);
    float f0 = __expf(m0 - mg), f1 = __expf(m1 - mg);
    float inv = 1.f / (f0 * l0 + f1 * l1);
    unsigned short* orow = simnew + ((size_t)b * NPAD + row) * NKP;
    for (int c = 0; c < NKP; ++c)
        orow[c] = f2bf((p0[(size_t)c * NPAD] * f0 + p1[(size_t)c * NPAD] * f1) * inv);
}

// ---------------- k_out ----------------
__global__ __launch_bounds__(256) void k_out(const unsigned short* __restrict__ simnew,
                                             const unsigned short* __restrict__ Zt,
                                             const float* __restrict__ bw,
                                             float* __restrict__ out)
{
    int b = blockIdx.z;
    int ng = blockIdx.x, og = blockIdx.y;
    int tid = threadIdx.x, w = tid >> 6, lane = tid & 63, lg = lane >> 4, lr = lane & 15;
    int o_row = (og * 4 + w) * 16;
    const unsigned short* za = Zt + ((size_t)b * CO + o_row + lr) * NKP + lg * 8;
    bf16x8 az[3];
#pragma unroll
    for (int ks = 0; ks < 3; ++ks) az[ks] = *reinterpret_cast<const bf16x8*>(za + ks * 32);
    f32x4 acc[4];
#pragma unroll
    for (int jn = 0; jn < 4; ++jn) acc[jn] = (f32x4){0.f, 0.f, 0.f, 0.f};
    const unsigned short* sb = simnew + ((size_t)b * NPAD + ng * 64) * NKP + lg * 8;
#pragma unroll
    for (int jn = 0; jn < 4; ++jn)
#pragma unroll
        for (int ks = 0; ks < 3; ++ks) {
            bf16x8 bfs = *reinterpret_cast<const bf16x8*>(sb + (size_t)(jn * 16 + lr) * NKP + ks * 32);
            acc[jn] = MFMA16(az[ks], bfs, acc[jn]);
        }
#pragma unroll
    for (int r = 0; r < 4; ++r) {
        int o = o_row + lg * 4 + r;
        float bias = bw[o];
        float* orow = out + ((size_t)b * CO + o) * NN;
#pragma unroll
        for (int jn = 0; jn < 4; ++jn) {
            int n = ng * 64 + jn * 16 + lr;
            if (n < NN) orow[n] = acc[jn][r] + bias;
        }
    }
}

extern "C" void kernel_launch(void* const* d_in, const int* in_sizes, int n_in,
                              void* d_out, int out_size, void* d_ws, size_t ws_size,
                              hipStream_t stream)
{
    const float* x     = (const float*)d_in[0];
    const float* Wk    = (const float*)d_in[1];
    const float* bk    = (const float*)d_in[2];
    const float* gamma = (const float*)d_in[3];
    const float* beta  = (const float*)d_in[4];
    const float* Wv    = (const float*)d_in[5];
    const float* bv    = (const float*)d_in[6];
    const float* Wv2   = (const float*)d_in[7];
    const float* bv2   = (const float*)d_in[8];
    const float* Ww    = (const float*)d_in[9];
    const float* bw    = (const float*)d_in[10];
    float* out = (float*)d_out;

    char* p = (char*)d_ws;
    unsigned short* xT     = (unsigned short*)p; p += (size_t)BB * NPAD * CINsz * 2;
    unsigned short* qkbf   = (unsigned short*)p; p += (size_t)BB * NPAD * CI * 2;
    unsigned short* value  = (unsigned short*)p; p += (size_t)BB * NPAD * CI * 2;
    unsigned short* svT    = (unsigned short*)p; p += (size_t)BB * NKP * NPAD * 2;
    unsigned short* simnew = (unsigned short*)p; p += (size_t)BB * NPAD * NKP * 2;
    unsigned short* Wkv    = (unsigned short*)p; p += (size_t)512 * 512 * 2;
    unsigned short* Wv2b   = (unsigned short*)p; p += (size_t)256 * 256 * 2;
    unsigned short* Wwb    = (unsigned short*)p; p += (size_t)512 * 256 * 2;
    unsigned short* pooled = (unsigned short*)p; p += (size_t)BB * NKP * CI * 2;
    unsigned short* v2f    = (unsigned short*)p; p += (size_t)BB * NKP * CI * 2;
    unsigned short* Zt     = (unsigned short*)p; p += (size_t)BB * CO * NKP * 2;
    float* bias2           = (float*)p;          p += 512 * 4;

    // partials alias xT (dead after k_qkv): 8 planes x 98 x NPAD fp32 = 12.65MB <= 16.5MB
    float* part = (float*)xT;

    k_prep<<<dim3(1794), 256, 0, stream>>>(Wk, bk, gamma, beta, Wv, bv, Wv2, Ww,
                                           Wkv, bias2, Wv2b, Wwb);
    k_tx<<<dim3(63, 8, BB), 256, 0, stream>>>(x, xT);
    k_qkv<<<dim3(126, BB), 256, 0, stream>>>(xT, Wkv, bias2, qkbf, value);
    k_pool<<<dim3(NKP, BB), 256, 0, stream>>>(value, pooled);
    k_v2<<<dim3(4, BB), 256, 0, stream>>>(pooled, Wv2b, bv2, v2f);
    k_Z<<<dim3(8, BB), 256, 0, stream>>>(Wwb, v2f, Zt);
    k_simv<<<dim3(63, BB), 256, 0, stream>>>(value, v2f, svT);
    k_flash<<<dim3(504), 256, 0, stream>>>(qkbf, svT, part);
    k_comb<<<dim3((4 * NPAD + 255) / 256), 256, 0, stream>>>(part, simnew);
    k_out<<<dim3(63, 8, BB), 256, 0, stream>>>(simnew, Zt, bw, out);
}